// Round 5
// baseline (607.749 us; speedup 1.0000x reference)
//
#include <hip/hip_runtime.h>
#include <cstdint>

// ---------------------------------------------------------------------------
// BotRGCN round 12: cut redundant plane traffic + launch count.
//  Round-11 lesson: k_gather is at its roofline (410 MB/pass @ 6.3 TB/s
//  effective, ideal coalescing) - untouched. Remaining slack is structural:
//   - k_egemm: embed fused into the embed GEMM. A-tiles are COMPUTED from x
//     (3.2 MB) straight into the LDS staging buffer in MFMA fragment layout,
//     replacing k_pre's 51.2 MB plane write + the GEMM's 51.2 MB re-read.
//   - k_scan_lb: single-pass decoupled-lookback scan replaces the 3-kernel
//     scan chain (ticket-ordered, agent-scope acquire/release).
//  CSR binning, gather, layer/cls GEMMs unchanged.
// ---------------------------------------------------------------------------

typedef short bf16x8 __attribute__((ext_vector_type(8)));
typedef float f32x4  __attribute__((ext_vector_type(4)));

__device__ __forceinline__ unsigned short f2bf(float f) {
    unsigned int u = __builtin_bit_cast(unsigned int, f);
    u += 0x7fff + ((u >> 16) & 1);          // RNE
    return (unsigned short)(u >> 16);
}
__device__ __forceinline__ float bf2f(unsigned short h) {
    unsigned int u = ((unsigned int)h) << 16;
    return __builtin_bit_cast(float, u);
}
__device__ __forceinline__ float lo16f(unsigned int u) {
    return __builtin_bit_cast(float, u << 16);
}
__device__ __forceinline__ float hi16f(unsigned int u) {
    return __builtin_bit_cast(float, u & 0xffff0000u);
}

__device__ __forceinline__ void gload_lds16(const void* g, void* l) {
    __builtin_amdgcn_global_load_lds(
        (const __attribute__((address_space(1))) void*)g,
        (__attribute__((address_space(3))) void*)l, 16, 0, 0);
}

// ---- fused embed GEMM: A computed from x into LDS, B gloaded ----
__global__ __launch_bounds__(256) void k_egemm(
    const float* __restrict__ x,
    const float* __restrict__ Wnum, const float* __restrict__ bnum,
    const float* __restrict__ Wcat, const float* __restrict__ bcat,
    const unsigned short* __restrict__ Bhi, const unsigned short* __restrict__ Blo,
    const float* __restrict__ bias, const float* __restrict__ prelu,
    unsigned short* __restrict__ C_hi, unsigned short* __restrict__ C_lo, int M)
{
    __shared__ unsigned short lds[2][32 * 512];   // 2 x 32 KB
    const int t = threadIdx.x;
    const int w = t >> 6, lane = t & 63;
    const int laneL = lane & 15, laneH = lane >> 4;
    const int wi = w >> 1, wj = w & 1;
    const int m0 = blockIdx.x * 128;
    const int Mm1 = M - 1;

    f32x4 acc[4][4];
    #pragma unroll
    for (int a = 0; a < 4; ++a)
        #pragma unroll
        for (int b = 0; b < 4; ++b)
            acc[a][b] = (f32x4){0.f, 0.f, 0.f, 0.f};

    // stage step s: compute A hi/lo fragments from x (slots 0,1), gload B (2,3)
    auto stage = [&](int s, unsigned short* buf) {
        int koff = s * 32;
        int k8 = koff + laneH * 8;            // 8 dims, never straddles 64
        #pragma unroll
        for (int c = 0; c < 2; ++c) {
            int j = w + c * 4;                // A chunk j in 0..7
            int rc = j * 16 + laneL;
            int row = (m0 + rc <= Mm1) ? (m0 + rc) : Mm1;
            const float4* xr = (const float4*)(x + (size_t)row * 8);
            float4 X0 = xr[0], X1 = xr[1];
            float a[8];
            if (k8 < 64) {
                const float4* bp = (const float4*)(bnum + k8);
                float4 b0 = bp[0], b1 = bp[1];
                a[0]=b0.x; a[1]=b0.y; a[2]=b0.z; a[3]=b0.w;
                a[4]=b1.x; a[5]=b1.y; a[6]=b1.z; a[7]=b1.w;
                float xs0 = X0.x, xs1 = X0.y, xs2 = X0.z, xs3 = X0.w, xs4 = X1.x;
                const float* wb = Wnum + k8;
                #pragma unroll
                for (int p = 0; p < 5; ++p) {
                    float xp = p==0?xs0 : p==1?xs1 : p==2?xs2 : p==3?xs3 : xs4;
                    const float4* wp = (const float4*)(wb + p * 64);
                    float4 w0 = wp[0], w1 = wp[1];
                    a[0]+=xp*w0.x; a[1]+=xp*w0.y; a[2]+=xp*w0.z; a[3]+=xp*w0.w;
                    a[4]+=xp*w1.x; a[5]+=xp*w1.y; a[6]+=xp*w1.z; a[7]+=xp*w1.w;
                }
            } else {
                int kk = k8 - 64;
                const float4* bp = (const float4*)(bcat + kk);
                float4 b0 = bp[0], b1 = bp[1];
                a[0]=b0.x; a[1]=b0.y; a[2]=b0.z; a[3]=b0.w;
                a[4]=b1.x; a[5]=b1.y; a[6]=b1.z; a[7]=b1.w;
                float xs0 = X1.y, xs1 = X1.z, xs2 = X1.w;
                const float* wb = Wcat + kk;
                #pragma unroll
                for (int p = 0; p < 3; ++p) {
                    float xp = p==0?xs0 : p==1?xs1 : xs2;
                    const float4* wp = (const float4*)(wb + p * 64);
                    float4 w0 = wp[0], w1 = wp[1];
                    a[0]+=xp*w0.x; a[1]+=xp*w0.y; a[2]+=xp*w0.z; a[3]+=xp*w0.w;
                    a[4]+=xp*w1.x; a[5]+=xp*w1.y; a[6]+=xp*w1.z; a[7]+=xp*w1.w;
                }
            }
            unsigned hw[4], lw[4];
            #pragma unroll
            for (int q = 0; q < 4; ++q) {
                float v0 = a[2*q]   >= 0.f ? a[2*q]   : 0.01f * a[2*q];
                float v1 = a[2*q+1] >= 0.f ? a[2*q+1] : 0.01f * a[2*q+1];
                unsigned short h0 = f2bf(v0), h1 = f2bf(v1);
                unsigned short l0 = f2bf(v0 - bf2f(h0)), l1 = f2bf(v1 - bf2f(h1));
                hw[q] = (unsigned)h0 | ((unsigned)h1 << 16);
                lw[q] = (unsigned)l0 | ((unsigned)l1 << 16);
            }
            uint4 ho, lo_;
            ho.x=hw[0]; ho.y=hw[1]; ho.z=hw[2]; ho.w=hw[3];
            lo_.x=lw[0]; lo_.y=lw[1]; lo_.z=lw[2]; lo_.w=lw[3];
            *(uint4*)&buf[(0 * 8 + j) * 512 + lane * 8] = ho;
            *(uint4*)&buf[(1 * 8 + j) * 512 + lane * 8] = lo_;
        }
        #pragma unroll
        for (int c = 4; c < 8; ++c) {
            int chunk = w + c * 4;            // 16..31 -> slots 2,3
            int slot = chunk >> 3, j = chunk & 7;
            const unsigned short* plane = (slot == 2) ? Bhi : Blo;
            int rc = j * 16 + laneL;
            const unsigned short* gp = plane + (size_t)rc * 128 + koff + laneH * 8;
            gload_lds16(gp, &buf[(slot * 8 + j) * 512]);
        }
    };

    stage(0, lds[0]);
    for (int s = 0; s < 4; ++s) {
        unsigned short* cur = lds[s & 1];
        unsigned short* nxt = lds[(s & 1) ^ 1];
        __syncthreads();
        if (s + 1 < 4) stage(s + 1, nxt);
        const bf16x8* fr = (const bf16x8*)cur;
        bf16x8 ah[4], al[4], bh[4], bl[4];
        #pragma unroll
        for (int mi = 0; mi < 4; ++mi) {
            ah[mi] = fr[(0 + wi * 4 + mi) * 64 + lane];
            al[mi] = fr[(8 + wi * 4 + mi) * 64 + lane];
        }
        #pragma unroll
        for (int nj = 0; nj < 4; ++nj) {
            bh[nj] = fr[(16 + wj * 4 + nj) * 64 + lane];
            bl[nj] = fr[(24 + wj * 4 + nj) * 64 + lane];
        }
        #pragma unroll
        for (int mi = 0; mi < 4; ++mi)
            #pragma unroll
            for (int nj = 0; nj < 4; ++nj) {
                acc[mi][nj] = __builtin_amdgcn_mfma_f32_16x16x32_bf16(
                    ah[mi], bh[nj], acc[mi][nj], 0, 0, 0);
                acc[mi][nj] = __builtin_amdgcn_mfma_f32_16x16x32_bf16(
                    ah[mi], bl[nj], acc[mi][nj], 0, 0, 0);
                acc[mi][nj] = __builtin_amdgcn_mfma_f32_16x16x32_bf16(
                    al[mi], bh[nj], acc[mi][nj], 0, 0, 0);
            }
    }

    // epilogue: bias + prelu -> hi/lo planes via LDS
    float bv[4], av[4];
    #pragma unroll
    for (int nj = 0; nj < 4; ++nj) {
        int col = wj * 64 + nj * 16 + laneL;
        bv[nj] = bias[col];
        av[nj] = prelu[col];
    }
    unsigned short* lp = &lds[0][0];
    __syncthreads();
    #pragma unroll
    for (int nj = 0; nj < 4; ++nj) {
        int col = wj * 64 + nj * 16 + laneL;
        #pragma unroll
        for (int mi = 0; mi < 4; ++mi)
            #pragma unroll
            for (int r = 0; r < 4; ++r) {
                int row = wi * 64 + mi * 16 + laneH * 4 + r;
                float v = acc[mi][nj][r] + bv[nj];
                v = v >= 0.f ? v : av[nj] * v;
                lp[row * 128 + col] = f2bf(v);
            }
    }
    __syncthreads();
    {
        const uint4* lsrc = (const uint4*)lp;
        #pragma unroll
        for (int it = 0; it < 8; ++it) {
            int idx = it * 256 + t;
            int row = idx >> 4, c = idx & 15;
            int m = m0 + row;
            if (m < M)
                ((uint4*)(C_hi + (size_t)m * 128))[c] = lsrc[idx];
        }
    }
    __syncthreads();
    #pragma unroll
    for (int nj = 0; nj < 4; ++nj) {
        int col = wj * 64 + nj * 16 + laneL;
        #pragma unroll
        for (int mi = 0; mi < 4; ++mi)
            #pragma unroll
            for (int r = 0; r < 4; ++r) {
                int row = wi * 64 + mi * 16 + laneH * 4 + r;
                float v = acc[mi][nj][r] + bv[nj];
                v = v >= 0.f ? v : av[nj] * v;
                unsigned short h = f2bf(v);
                lp[row * 128 + col] = f2bf(v - bf2f(h));
            }
    }
    __syncthreads();
    {
        const uint4* lsrc = (const uint4*)lp;
        #pragma unroll
        for (int it = 0; it < 8; ++it) {
            int idx = it * 256 + t;
            int row = idx >> 4, c = idx & 15;
            int m = m0 + row;
            if (m < M)
                ((uint4*)(C_lo + (size_t)m * 128))[c] = lsrc[idx];
        }
    }
}

// ---- pass A: per-block bin histogram, ROW-major (coalesced) output ----
__global__ __launch_bounds__(256) void k_hist(
    const int* __restrict__ ei, const int* __restrict__ et,
    int* __restrict__ cntmatT, int E, int N, int NBINS)
{
    __shared__ int hist[1024];
    const int t = threadIdx.x, blk = blockIdx.x;
    for (int i = t; i < NBINS; i += 256) hist[i] = 0;
    __syncthreads();
    #pragma unroll
    for (int j = 0; j < 8; ++j) {
        int e = blk * 2048 + j * 256 + t;
        if (e < E) atomicAdd(&hist[(et[e] * N + ei[E + e]) >> 8], 1);
    }
    __syncthreads();
    for (int i = t; i < NBINS; i += 256)
        cntmatT[(size_t)blk * NBINS + i] = hist[i];
}

// ---- LDS-tiled int transpose: dst[c*R + r] = src[r*C + c] ----
__global__ __launch_bounds__(256) void k_transpose(
    const int* __restrict__ src, int* __restrict__ dst, int R, int C)
{
    __shared__ int tile[32][33];
    int ctiles = (C + 31) >> 5;
    int bx = blockIdx.x % ctiles;
    int by = blockIdx.x / ctiles;
    int tc = threadIdx.x & 31, tr = threadIdx.x >> 5;
    int c0 = bx * 32, r0 = by * 32;
    #pragma unroll
    for (int i = 0; i < 32; i += 8) {
        int r = r0 + tr + i, c = c0 + tc;
        if (r < R && c < C) tile[tr + i][tc] = src[(size_t)r * C + c];
    }
    __syncthreads();
    #pragma unroll
    for (int i = 0; i < 32; i += 8) {
        int r = r0 + tc;
        int c = c0 + tr + i;
        if (r < R && c < C) dst[(size_t)c * R + r] = tile[tc][tr + i];
    }
}

// ---- weight split+transpose ----
struct WArgs {
    const float* W[8];
    unsigned short* hi[8];
    unsigned short* lo[8];
};
__global__ __launch_bounds__(256) void k_wsplit(WArgs a)
{
    int part = blockIdx.y;
    int idx = blockIdx.x * 256 + threadIdx.x;
    int n = idx >> 7, k = idx & 127;
    float v = a.W[part][(size_t)k * 128 + n];
    unsigned short h = f2bf(v);
    a.hi[part][(size_t)n * 128 + k] = h;
    a.lo[part][(size_t)n * 128 + k] = f2bf(v - bf2f(h));
}

// ---- single-pass decoupled-lookback exclusive scan (4 ints/thread) ----
__global__ __launch_bounds__(256) void k_scan_lb(
    const int* __restrict__ src, int* __restrict__ dst,
    unsigned long long* __restrict__ part, int* __restrict__ tick, int n)
{
    __shared__ int s[256];
    __shared__ int bidsh;
    __shared__ int exsh;
    const int t = threadIdx.x;
    if (t == 0) bidsh = atomicAdd(tick, 1);
    __syncthreads();
    const int bid = bidsh;
    const int i0 = bid * 1024 + t * 4;
    int v[4];
    if (i0 + 3 < n) {
        int4 q = *(const int4*)(src + i0);
        v[0]=q.x; v[1]=q.y; v[2]=q.z; v[3]=q.w;
    } else {
        #pragma unroll
        for (int k = 0; k < 4; ++k) v[k] = (i0 + k < n) ? src[i0 + k] : 0;
    }
    int tsum = v[0] + v[1] + v[2] + v[3];
    s[t] = tsum;
    __syncthreads();
    #pragma unroll
    for (int d = 1; d < 256; d <<= 1) {
        int add = (t >= d) ? s[t - d] : 0;
        __syncthreads();
        s[t] += add;
        __syncthreads();
    }
    int texcl = s[t] - tsum;
    int total = s[255];
    if (t == 0) {
        unsigned long long pub = (unsigned long long)(unsigned)total |
                                 (bid == 0 ? (2ULL << 32) : (1ULL << 32));
        __hip_atomic_store(&part[bid], pub, __ATOMIC_RELEASE, __HIP_MEMORY_SCOPE_AGENT);
        int ex = 0;
        if (bid > 0) {
            int j = bid - 1;
            while (true) {
                unsigned long long pv = __hip_atomic_load(
                    &part[j], __ATOMIC_ACQUIRE, __HIP_MEMORY_SCOPE_AGENT);
                unsigned st = (unsigned)(pv >> 32);
                if (st == 0) continue;
                ex += (int)(unsigned)pv;
                if (st == 2) break;
                --j;
            }
            __hip_atomic_store(&part[bid],
                (unsigned long long)(unsigned)(ex + total) | (2ULL << 32),
                __ATOMIC_RELEASE, __HIP_MEMORY_SCOPE_AGENT);
        }
        exsh = ex;
    }
    __syncthreads();
    int run = exsh + texcl;
    int4 o;
    o.x = run;
    o.y = run + v[0];
    o.z = run + v[0] + v[1];
    o.w = run + v[0] + v[1] + v[2];
    if (i0 + 3 < n) {
        *(int4*)(dst + i0) = o;
    } else {
        int pr = run;
        #pragma unroll
        for (int k = 0; k < 4; ++k)
            if (i0 + k < n) { dst[i0 + k] = pr; pr += v[k]; }
    }
}

// ---- pass C: scatter edges into bin-contiguous ebuf (LDS cursors) ----
__global__ __launch_bounds__(256) void k_binscatter(
    const int* __restrict__ ei, const int* __restrict__ et,
    const int* __restrict__ cntscanT, int* __restrict__ ebuf,
    int E, int N, int NBINS)
{
    __shared__ int base[1024];
    const int t = threadIdx.x;
    const int blk = blockIdx.x;
    for (int i = t; i < NBINS; i += 256)
        base[i] = cntscanT[(size_t)blk * NBINS + i];
    __syncthreads();
    #pragma unroll
    for (int j = 0; j < 8; ++j) {
        int e = blk * 2048 + j * 256 + t;
        if (e < E) {
            unsigned src = (unsigned)ei[e];
            int seg = et[e] * N + ei[E + e];
            int pos = atomicAdd(&base[seg >> 8], 1);     // LDS atomic
            ebuf[pos] = (int)(((unsigned)(seg & 255) << 24) | src);
        }
    }
}

// ---- pass D: per-bin exact CSR (256 segs/bin, LDS count + scan) ----
__global__ __launch_bounds__(256) void k_bincsr(
    const int* __restrict__ cntscan, const int* __restrict__ ebuf,
    int* __restrict__ deg, int* __restrict__ off, int* __restrict__ esrc,
    int E, int nseg, int NBLK, int NBINS)
{
    __shared__ int cnt[256];
    __shared__ int pfx[256];
    __shared__ int cur[256];
    const int b = blockIdx.x;
    const int t = threadIdx.x;
    const int est = cntscan[(size_t)b * NBLK];
    const int een = (b + 1 < NBINS) ? cntscan[(size_t)(b + 1) * NBLK] : E;
    cnt[t] = 0;
    __syncthreads();
    for (int e = est + t; e < een; e += 256)
        atomicAdd(&cnt[((unsigned)ebuf[e]) >> 24], 1);
    __syncthreads();
    int v = cnt[t];
    pfx[t] = v;
    __syncthreads();
    #pragma unroll
    for (int d = 1; d < 256; d <<= 1) {
        int add = (t >= d) ? pfx[t - d] : 0;
        __syncthreads();
        pfx[t] += add;
        __syncthreads();
    }
    int o = est + pfx[t] - v;
    int seg = b * 256 + t;
    if (seg < nseg) { deg[seg] = v; off[seg] = o; }
    cur[t] = o;
    __syncthreads();
    for (int e = est + t; e < een; e += 256) {
        unsigned u = (unsigned)ebuf[e];
        int p = atomicAdd(&cur[u >> 24], 1);             // LDS atomic
        esrc[p] = (int)(u & 0xffffffu);
    }
}

// ---- mean aggregation, bf16 hi plane, quarter-wave rows ----
__global__ __launch_bounds__(256) void k_gather(
    const unsigned short* __restrict__ h_hi,
    const int* __restrict__ esrc,
    const int* __restrict__ off, const int* __restrict__ deg,
    unsigned short* __restrict__ a_hi, int nseg)
{
    int i = blockIdx.x * 8 + (threadIdx.x >> 5);
    if (i >= nseg) return;
    int l32 = threadIdx.x & 31;
    int q = l32 >> 4;
    int l16 = l32 & 15;
    int cnt = deg[i], st = off[i];
    const uint4* hp = (const uint4*)h_hi;
    float a0 = 0.f, a1 = 0.f, a2 = 0.f, a3 = 0.f;
    float a4 = 0.f, a5 = 0.f, a6 = 0.f, a7 = 0.f;
    int e = q;
    for (; e + 6 < cnt; e += 8) {
        int i0 = esrc[st + e + 0];
        int i1 = esrc[st + e + 2];
        int i2 = esrc[st + e + 4];
        int i3 = esrc[st + e + 6];
        uint4 u0 = hp[(size_t)i0 * 16 + l16];
        uint4 u1 = hp[(size_t)i1 * 16 + l16];
        uint4 u2 = hp[(size_t)i2 * 16 + l16];
        uint4 u3 = hp[(size_t)i3 * 16 + l16];
        a0 += lo16f(u0.x); a1 += hi16f(u0.x); a2 += lo16f(u0.y); a3 += hi16f(u0.y);
        a4 += lo16f(u0.z); a5 += hi16f(u0.z); a6 += lo16f(u0.w); a7 += hi16f(u0.w);
        a0 += lo16f(u1.x); a1 += hi16f(u1.x); a2 += lo16f(u1.y); a3 += hi16f(u1.y);
        a4 += lo16f(u1.z); a5 += hi16f(u1.z); a6 += lo16f(u1.w); a7 += hi16f(u1.w);
        a0 += lo16f(u2.x); a1 += hi16f(u2.x); a2 += lo16f(u2.y); a3 += hi16f(u2.y);
        a4 += lo16f(u2.z); a5 += hi16f(u2.z); a6 += lo16f(u2.w); a7 += hi16f(u2.w);
        a0 += lo16f(u3.x); a1 += hi16f(u3.x); a2 += lo16f(u3.y); a3 += hi16f(u3.y);
        a4 += lo16f(u3.z); a5 += hi16f(u3.z); a6 += lo16f(u3.w); a7 += hi16f(u3.w);
    }
    for (; e < cnt; e += 2) {
        uint4 u = hp[(size_t)esrc[st + e] * 16 + l16];
        a0 += lo16f(u.x); a1 += hi16f(u.x); a2 += lo16f(u.y); a3 += hi16f(u.y);
        a4 += lo16f(u.z); a5 += hi16f(u.z); a6 += lo16f(u.w); a7 += hi16f(u.w);
    }
    a0 += __shfl_xor(a0, 16, 64);
    a1 += __shfl_xor(a1, 16, 64);
    a2 += __shfl_xor(a2, 16, 64);
    a3 += __shfl_xor(a3, 16, 64);
    a4 += __shfl_xor(a4, 16, 64);
    a5 += __shfl_xor(a5, 16, 64);
    a6 += __shfl_xor(a6, 16, 64);
    a7 += __shfl_xor(a7, 16, 64);
    if (q == 0) {
        float inv = 1.0f / (float)(cnt > 1 ? cnt : 1);
        uint4 o;
        o.x = (unsigned int)f2bf(a0 * inv) | ((unsigned int)f2bf(a1 * inv) << 16);
        o.y = (unsigned int)f2bf(a2 * inv) | ((unsigned int)f2bf(a3 * inv) << 16);
        o.z = (unsigned int)f2bf(a4 * inv) | ((unsigned int)f2bf(a5 * inv) << 16);
        o.w = (unsigned int)f2bf(a6 * inv) | ((unsigned int)f2bf(a7 * inv) << 16);
        ((uint4*)a_hi)[(size_t)i * 16 + l16] = o;
    }
}

// ---- pipelined split-bf16 MFMA GEMM ----
struct GArgs {
    const unsigned short* A_hi[3];
    const unsigned short* A_lo[3];
    const unsigned short* B_hi[3];   // transposed [n][k]
    const unsigned short* B_lo[3];
    int alo[3];
    int blo[3];
    const float* bias;
    const float* prelu;
    float* Cf;                       // if non-null: fp32 output
    unsigned short* C_hi;
    unsigned short* C_lo;
    int M;
    int P;
};

__global__ __launch_bounds__(256) void k_mgemm(GArgs g)
{
    __shared__ unsigned short lds[2][32 * 512];   // 2 x 32 KB
    const int t = threadIdx.x;
    const int w = t >> 6, lane = t & 63;
    const int laneL = lane & 15, laneH = lane >> 4;
    const int wi = w >> 1, wj = w & 1;
    const int m0 = blockIdx.x * 128;
    const int Mm1 = g.M - 1;
    const int S = g.P * 4;

    f32x4 acc[4][4];
    #pragma unroll
    for (int a = 0; a < 4; ++a)
        #pragma unroll
        for (int b = 0; b < 4; ++b)
            acc[a][b] = (f32x4){0.f, 0.f, 0.f, 0.f};

    auto stage = [&](int s, unsigned short* buf) {
        int p = s >> 2, koff = (s & 3) * 32;
        const unsigned short* tp[4];
        tp[0] = g.A_hi[p];
        tp[1] = g.alo[p] ? g.A_lo[p] : nullptr;
        tp[2] = g.B_hi[p];
        tp[3] = g.blo[p] ? g.B_lo[p] : nullptr;
        #pragma unroll
        for (int c = 0; c < 8; ++c) {
            int chunk = w + c * 4;            // 0..31
            int slot = chunk >> 3, j = chunk & 7;
            const unsigned short* plane = tp[slot];
            if (!plane) continue;
            int rc = j * 16 + laneL;
            int row = (slot < 2) ? (m0 + rc <= Mm1 ? m0 + rc : Mm1) : rc;
            const unsigned short* gp = plane + (size_t)row * 128 + koff + laneH * 8;
            gload_lds16(gp, &buf[(slot * 8 + j) * 512]);
        }
    };

    stage(0, lds[0]);
    for (int s = 0; s < S; ++s) {
        unsigned short* cur = lds[s & 1];
        unsigned short* nxt = lds[(s & 1) ^ 1];
        __syncthreads();                      // drains stage(s); frees nxt
        if (s + 1 < S) stage(s + 1, nxt);     // overlaps with compute below
        int p = s >> 2;
        const bool hasAlo = g.alo[p] != 0;
        const bool hasBlo = g.blo[p] != 0;
        const bf16x8* fr = (const bf16x8*)cur;
        bf16x8 ah[4], al[4], bh[4], bl[4];
        #pragma unroll
        for (int mi = 0; mi < 4; ++mi)
            ah[mi] = fr[(0 + wi * 4 + mi) * 64 + lane];
        if (hasAlo) {
            #pragma unroll
            for (int mi = 0; mi < 4; ++mi)
                al[mi] = fr[(8 + wi * 4 + mi) * 64 + lane];
        }
        #pragma unroll
        for (int nj = 0; nj < 4; ++nj)
            bh[nj] = fr[(16 + wj * 4 + nj) * 64 + lane];
        if (hasBlo) {
            #pragma unroll
            for (int nj = 0; nj < 4; ++nj)
                bl[nj] = fr[(24 + wj * 4 + nj) * 64 + lane];
        }
        #pragma unroll
        for (int mi = 0; mi < 4; ++mi)
            #pragma unroll
            for (int nj = 0; nj < 4; ++nj) {
                acc[mi][nj] = __builtin_amdgcn_mfma_f32_16x16x32_bf16(
                    ah[mi], bh[nj], acc[mi][nj], 0, 0, 0);
                if (hasBlo)
                    acc[mi][nj] = __builtin_amdgcn_mfma_f32_16x16x32_bf16(
                        ah[mi], bl[nj], acc[mi][nj], 0, 0, 0);
                if (hasAlo)
                    acc[mi][nj] = __builtin_amdgcn_mfma_f32_16x16x32_bf16(
                        al[mi], bh[nj], acc[mi][nj], 0, 0, 0);
            }
    }

    // ---- epilogue: acc -> LDS (C layout) -> coalesced stores ----
    const bool hasPrelu = (g.prelu != nullptr);
    float bv[4], av[4];
    #pragma unroll
    for (int nj = 0; nj < 4; ++nj) {
        int col = wj * 64 + nj * 16 + laneL;
        bv[nj] = g.bias[col];
        av[nj] = hasPrelu ? g.prelu[col] : 0.f;
    }

    if (g.Cf) {
        float* lf = (float*)&lds[0][0];       // 128x128 f32 = 64 KB
        __syncthreads();
        #pragma unroll
        for (int nj = 0; nj < 4; ++nj) {
            int col = wj * 64 + nj * 16 + laneL;
            #pragma unroll
            for (int mi = 0; mi < 4; ++mi)
                #pragma unroll
                for (int r = 0; r < 4; ++r) {
                    int row = wi * 64 + mi * 16 + laneH * 4 + r;
                    float v = acc[mi][nj][r] + bv[nj];
                    lf[row * 128 + col] = v;
                }
        }
        __syncthreads();
        const uint4* lsrc = (const uint4*)lf;
        #pragma unroll
        for (int it = 0; it < 16; ++it) {
            int idx = it * 256 + t;          // 4096 uint4
            int row = idx >> 5, c = idx & 31;
            int m = m0 + row;
            if (m < g.M)
                ((uint4*)(g.Cf + (size_t)m * 128))[c] = lsrc[idx];
        }
    } else {
        unsigned short* lp = &lds[0][0];     // 128x128 ushort = 32 KB
        // hi pass
        __syncthreads();
        #pragma unroll
        for (int nj = 0; nj < 4; ++nj) {
            int col = wj * 64 + nj * 16 + laneL;
            #pragma unroll
            for (int mi = 0; mi < 4; ++mi)
                #pragma unroll
                for (int r = 0; r < 4; ++r) {
                    int row = wi * 64 + mi * 16 + laneH * 4 + r;
                    float v = acc[mi][nj][r] + bv[nj];
                    if (hasPrelu) v = v >= 0.f ? v : av[nj] * v;
                    lp[row * 128 + col] = f2bf(v);
                }
        }
        __syncthreads();
        {
            const uint4* lsrc = (const uint4*)lp;
            #pragma unroll
            for (int it = 0; it < 8; ++it) {
                int idx = it * 256 + t;      // 2048 uint4
                int row = idx >> 4, c = idx & 15;
                int m = m0 + row;
                if (m < g.M)
                    ((uint4*)(g.C_hi + (size_t)m * 128))[c] = lsrc[idx];
            }
        }
        // lo pass
        __syncthreads();
        #pragma unroll
        for (int nj = 0; nj < 4; ++nj) {
            int col = wj * 64 + nj * 16 + laneL;
            #pragma unroll
            for (int mi = 0; mi < 4; ++mi)
                #pragma unroll
                for (int r = 0; r < 4; ++r) {
                    int row = wi * 64 + mi * 16 + laneH * 4 + r;
                    float v = acc[mi][nj][r] + bv[nj];
                    if (hasPrelu) v = v >= 0.f ? v : av[nj] * v;
                    unsigned short h = f2bf(v);
                    lp[row * 128 + col] = f2bf(v - bf2f(h));
                }
        }
        __syncthreads();
        {
            const uint4* lsrc = (const uint4*)lp;
            #pragma unroll
            for (int it = 0; it < 8; ++it) {
                int idx = it * 256 + t;
                int row = idx >> 4, c = idx & 15;
                int m = m0 + row;
                if (m < g.M)
                    ((uint4*)(g.C_lo + (size_t)m * 128))[c] = lsrc[idx];
            }
        }
    }
}

extern "C" void kernel_launch(void* const* d_in, const int* in_sizes, int n_in,
                              void* d_out, int out_size, void* d_ws, size_t ws_size,
                              hipStream_t stream) {
    const float* x      = (const float*)d_in[0];
    const int*   ei     = (const int*)d_in[1];
    const int*   et     = (const int*)d_in[2];
    const float* Wnum   = (const float*)d_in[3];
    const float* bnum   = (const float*)d_in[4];
    const float* Wcat   = (const float*)d_in[5];
    const float* bcat   = (const float*)d_in[6];
    const float* Win    = (const float*)d_in[7];
    const float* bin    = (const float*)d_in[8];
    const float* pa     = (const float*)d_in[9];
    const float* Wrel1  = (const float*)d_in[10];
    const float* Wroot1 = (const float*)d_in[11];
    const float* brg1   = (const float*)d_in[12];
    const float* Wrel2  = (const float*)d_in[13];
    const float* Wroot2 = (const float*)d_in[14];
    const float* brg2   = (const float*)d_in[15];
    const float* Wcls   = (const float*)d_in[16];
    const float* bcls   = (const float*)d_in[17];
    float* out = (float*)d_out;

    const int N = in_sizes[0] / 8;
    const int E = in_sizes[1] / 2;
    const int nseg = 2 * N;
    const size_t NH = (size_t)N * 128;

    const int NBLK  = (E + 2047) / 2048;        // edge blocks (782)
    const int NBINS = (nseg + 255) / 256;       // coarse bins (782)
    const long long L = (long long)NBINS * NBLK;

    char* w = (char*)d_ws;
    unsigned short* h0_hi = (unsigned short*)w;  w += NH * 2;
    unsigned short* h0_lo = (unsigned short*)w;  w += NH * 2;
    unsigned short* agg_hi = (unsigned short*)w; w += 2 * NH * 2;
    int* deg      = (int*)w;  w += (size_t)nseg * 4;
    int* off      = (int*)w;  w += (size_t)nseg * 4;
    int* cntmatT  = (int*)w;  w += (size_t)L * 4;   // [blk][bin]
    int* cntmat   = (int*)w;  w += (size_t)L * 4;   // [bin][blk]
    int* cntscan  = (int*)w;  w += (size_t)L * 4;   // [bin][blk] scanned
    int* cntscanT = (int*)w;  w += (size_t)L * 4;   // [blk][bin] scanned
    int* esrc     = (int*)w;  w += (size_t)E * 4;
    int* bsum     = (int*)w;  w += 4096 * 4;        // scan_lb part+tick
    unsigned short* wplanes = (unsigned short*)w;  w += 8 * 2 * 16384 * 2;

    unsigned short* h1_hi = (unsigned short*)d_out;
    unsigned short* h1_lo = h1_hi + NH;
    unsigned short* h2_hi = h0_hi;
    unsigned short* h2_lo = h0_lo;
    int* ebuf = (int*)d_out;   // E ints; dead before h1 is written (layer-1 GEMM)

    unsigned long long* part = (unsigned long long*)bsum;  // up to 1024 entries
    int* tick = (int*)(bsum + 2048);                        // after part region

    unsigned short* whi[8];
    unsigned short* wlo[8];
    for (int i = 0; i < 8; ++i) {
        whi[i] = wplanes + (size_t)i * 2 * 16384;
        wlo[i] = whi[i] + 16384;
    }

    hipMemsetAsync(bsum, 0, 4096 * 4, stream);   // zero part[] + tick

    {
        WArgs a;
        a.W[0] = Win;   a.W[1] = Wroot1; a.W[2] = Wrel1; a.W[3] = Wrel1 + 16384;
        a.W[4] = Wroot2; a.W[5] = Wrel2; a.W[6] = Wrel2 + 16384; a.W[7] = Wcls;
        for (int i = 0; i < 8; ++i) { a.hi[i] = whi[i]; a.lo[i] = wlo[i]; }
        k_wsplit<<<dim3(64, 8), 256, 0, stream>>>(a);
    }

    const int gm = (N + 127) / 128;
    const int gg = (nseg + 7) / 8;

    // CSR pipeline
    k_hist<<<NBLK, 256, 0, stream>>>(ei, et, cntmatT, E, N, NBINS);

    const int rt = (NBLK + 31) / 32, ct = (NBINS + 31) / 32;
    k_transpose<<<rt * ct, 256, 0, stream>>>(cntmatT, cntmat, NBLK, NBINS);

    const int nlb = (int)((L + 1023) / 1024);
    k_scan_lb<<<nlb, 256, 0, stream>>>(cntmat, cntscan, part, tick, (int)L);

    k_transpose<<<ct * rt, 256, 0, stream>>>(cntscan, cntscanT, NBINS, NBLK);

    k_binscatter<<<NBLK, 256, 0, stream>>>(ei, et, cntscanT, ebuf, E, N, NBINS);
    k_bincsr<<<NBINS, 256, 0, stream>>>(cntscan, ebuf, deg, off, esrc, E, nseg, NBLK, NBINS);

    // fused embed GEMM (x -> h0 planes)
    k_egemm<<<gm, 256, 0, stream>>>(x, Wnum, bnum, Wcat, bcat,
                                    whi[0], wlo[0], bin, pa,
                                    h0_hi, h0_lo, N);

    // layer 1
    k_gather<<<gg, 256, 0, stream>>>(h0_hi, esrc, off, deg, agg_hi, nseg);
    {
        GArgs g = {};
        g.A_hi[0] = h0_hi;       g.A_lo[0] = h0_lo;  g.alo[0] = 1; g.blo[0] = 1;
        g.A_hi[1] = agg_hi;      g.alo[1] = 0;       g.blo[1] = 0;
        g.A_hi[2] = agg_hi + NH; g.alo[2] = 0;       g.blo[2] = 0;
        g.B_hi[0] = whi[1]; g.B_lo[0] = wlo[1];
        g.B_hi[1] = whi[2]; g.B_lo[1] = wlo[2];
        g.B_hi[2] = whi[3]; g.B_lo[2] = wlo[3];
        g.bias = brg1; g.prelu = nullptr;
        g.Cf = nullptr; g.C_hi = h1_hi; g.C_lo = h1_lo;
        g.M = N; g.P = 3;
        k_mgemm<<<gm, 256, 0, stream>>>(g);
    }
    // layer 2
    k_gather<<<gg, 256, 0, stream>>>(h1_hi, esrc, off, deg, agg_hi, nseg);
    {
        GArgs g = {};
        g.A_hi[0] = h1_hi;       g.A_lo[0] = h1_lo;  g.alo[0] = 1; g.blo[0] = 1;
        g.A_hi[1] = agg_hi;      g.alo[1] = 0;       g.blo[1] = 0;
        g.A_hi[2] = agg_hi + NH; g.alo[2] = 0;       g.blo[2] = 0;
        g.B_hi[0] = whi[4]; g.B_lo[0] = wlo[4];
        g.B_hi[1] = whi[5]; g.B_lo[1] = wlo[5];
        g.B_hi[2] = whi[6]; g.B_lo[2] = wlo[6];
        g.bias = brg2; g.prelu = nullptr;
        g.Cf = nullptr; g.C_hi = h2_hi; g.C_lo = h2_lo;
        g.M = N; g.P = 3;
        k_mgemm<<<gm, 256, 0, stream>>>(g);
    }
    // classifier
    {
        GArgs g = {};
        g.A_hi[0] = h2_hi; g.A_lo[0] = h2_lo; g.alo[0] = 1; g.blo[0] = 1;
        g.B_hi[0] = whi[7]; g.B_lo[0] = wlo[7];
        g.bias = bcls; g.prelu = nullptr;
        g.Cf = out; g.C_hi = nullptr; g.C_lo = nullptr;
        g.M = N; g.P = 1;
        k_mgemm<<<gm, 256, 0, stream>>>(g);
    }
}

// Round 6
// 474.730 us; speedup vs baseline: 1.2802x; 1.2802x over previous
//
#include <hip/hip_runtime.h>
#include <cstdint>

// ---------------------------------------------------------------------------
// BotRGCN round 13: revert scan to 3-kernel chain; keep fused embed GEMM.
//  Round-12 lesson: decoupled-lookback scan = 598-block SERIAL chain through
//  device-scope flags; each hop is a cross-XCD coherence round-trip (~270 ns)
//  -> 163 us with every pipe idle. On MI355X (8 non-coherent per-XCD L2s),
//  never serialize the grid through global atomics. The 3-pass scan chain is
//  3 tiny BW-bound passes (~2.4 MB each) and has no serial chain.
//  k_egemm (embed fused into GEMM staging, round 12) kept: it passed with
//  identical absmax and removed k_pre + 100 MB of plane round-trip.
// ---------------------------------------------------------------------------

typedef short bf16x8 __attribute__((ext_vector_type(8)));
typedef float f32x4  __attribute__((ext_vector_type(4)));

__device__ __forceinline__ unsigned short f2bf(float f) {
    unsigned int u = __builtin_bit_cast(unsigned int, f);
    u += 0x7fff + ((u >> 16) & 1);          // RNE
    return (unsigned short)(u >> 16);
}
__device__ __forceinline__ float bf2f(unsigned short h) {
    unsigned int u = ((unsigned int)h) << 16;
    return __builtin_bit_cast(float, u);
}
__device__ __forceinline__ float lo16f(unsigned int u) {
    return __builtin_bit_cast(float, u << 16);
}
__device__ __forceinline__ float hi16f(unsigned int u) {
    return __builtin_bit_cast(float, u & 0xffff0000u);
}

__device__ __forceinline__ void gload_lds16(const void* g, void* l) {
    __builtin_amdgcn_global_load_lds(
        (const __attribute__((address_space(1))) void*)g,
        (__attribute__((address_space(3))) void*)l, 16, 0, 0);
}

// ---- fused embed GEMM: A computed from x into LDS, B gloaded ----
__global__ __launch_bounds__(256) void k_egemm(
    const float* __restrict__ x,
    const float* __restrict__ Wnum, const float* __restrict__ bnum,
    const float* __restrict__ Wcat, const float* __restrict__ bcat,
    const unsigned short* __restrict__ Bhi, const unsigned short* __restrict__ Blo,
    const float* __restrict__ bias, const float* __restrict__ prelu,
    unsigned short* __restrict__ C_hi, unsigned short* __restrict__ C_lo, int M)
{
    __shared__ unsigned short lds[2][32 * 512];   // 2 x 32 KB
    const int t = threadIdx.x;
    const int w = t >> 6, lane = t & 63;
    const int laneL = lane & 15, laneH = lane >> 4;
    const int wi = w >> 1, wj = w & 1;
    const int m0 = blockIdx.x * 128;
    const int Mm1 = M - 1;

    f32x4 acc[4][4];
    #pragma unroll
    for (int a = 0; a < 4; ++a)
        #pragma unroll
        for (int b = 0; b < 4; ++b)
            acc[a][b] = (f32x4){0.f, 0.f, 0.f, 0.f};

    // stage step s: compute A hi/lo fragments from x (slots 0,1), gload B (2,3)
    auto stage = [&](int s, unsigned short* buf) {
        int koff = s * 32;
        int k8 = koff + laneH * 8;            // 8 dims, never straddles 64
        #pragma unroll
        for (int c = 0; c < 2; ++c) {
            int j = w + c * 4;                // A chunk j in 0..7
            int rc = j * 16 + laneL;
            int row = (m0 + rc <= Mm1) ? (m0 + rc) : Mm1;
            const float4* xr = (const float4*)(x + (size_t)row * 8);
            float4 X0 = xr[0], X1 = xr[1];
            float a[8];
            if (k8 < 64) {
                const float4* bp = (const float4*)(bnum + k8);
                float4 b0 = bp[0], b1 = bp[1];
                a[0]=b0.x; a[1]=b0.y; a[2]=b0.z; a[3]=b0.w;
                a[4]=b1.x; a[5]=b1.y; a[6]=b1.z; a[7]=b1.w;
                float xs0 = X0.x, xs1 = X0.y, xs2 = X0.z, xs3 = X0.w, xs4 = X1.x;
                const float* wb = Wnum + k8;
                #pragma unroll
                for (int p = 0; p < 5; ++p) {
                    float xp = p==0?xs0 : p==1?xs1 : p==2?xs2 : p==3?xs3 : xs4;
                    const float4* wp = (const float4*)(wb + p * 64);
                    float4 w0 = wp[0], w1 = wp[1];
                    a[0]+=xp*w0.x; a[1]+=xp*w0.y; a[2]+=xp*w0.z; a[3]+=xp*w0.w;
                    a[4]+=xp*w1.x; a[5]+=xp*w1.y; a[6]+=xp*w1.z; a[7]+=xp*w1.w;
                }
            } else {
                int kk = k8 - 64;
                const float4* bp = (const float4*)(bcat + kk);
                float4 b0 = bp[0], b1 = bp[1];
                a[0]=b0.x; a[1]=b0.y; a[2]=b0.z; a[3]=b0.w;
                a[4]=b1.x; a[5]=b1.y; a[6]=b1.z; a[7]=b1.w;
                float xs0 = X1.y, xs1 = X1.z, xs2 = X1.w;
                const float* wb = Wcat + kk;
                #pragma unroll
                for (int p = 0; p < 3; ++p) {
                    float xp = p==0?xs0 : p==1?xs1 : xs2;
                    const float4* wp = (const float4*)(wb + p * 64);
                    float4 w0 = wp[0], w1 = wp[1];
                    a[0]+=xp*w0.x; a[1]+=xp*w0.y; a[2]+=xp*w0.z; a[3]+=xp*w0.w;
                    a[4]+=xp*w1.x; a[5]+=xp*w1.y; a[6]+=xp*w1.z; a[7]+=xp*w1.w;
                }
            }
            unsigned hw[4], lw[4];
            #pragma unroll
            for (int q = 0; q < 4; ++q) {
                float v0 = a[2*q]   >= 0.f ? a[2*q]   : 0.01f * a[2*q];
                float v1 = a[2*q+1] >= 0.f ? a[2*q+1] : 0.01f * a[2*q+1];
                unsigned short h0 = f2bf(v0), h1 = f2bf(v1);
                unsigned short l0 = f2bf(v0 - bf2f(h0)), l1 = f2bf(v1 - bf2f(h1));
                hw[q] = (unsigned)h0 | ((unsigned)h1 << 16);
                lw[q] = (unsigned)l0 | ((unsigned)l1 << 16);
            }
            uint4 ho, lo_;
            ho.x=hw[0]; ho.y=hw[1]; ho.z=hw[2]; ho.w=hw[3];
            lo_.x=lw[0]; lo_.y=lw[1]; lo_.z=lw[2]; lo_.w=lw[3];
            *(uint4*)&buf[(0 * 8 + j) * 512 + lane * 8] = ho;
            *(uint4*)&buf[(1 * 8 + j) * 512 + lane * 8] = lo_;
        }
        #pragma unroll
        for (int c = 4; c < 8; ++c) {
            int chunk = w + c * 4;            // 16..31 -> slots 2,3
            int slot = chunk >> 3, j = chunk & 7;
            const unsigned short* plane = (slot == 2) ? Bhi : Blo;
            int rc = j * 16 + laneL;
            const unsigned short* gp = plane + (size_t)rc * 128 + koff + laneH * 8;
            gload_lds16(gp, &buf[(slot * 8 + j) * 512]);
        }
    };

    stage(0, lds[0]);
    for (int s = 0; s < 4; ++s) {
        unsigned short* cur = lds[s & 1];
        unsigned short* nxt = lds[(s & 1) ^ 1];
        __syncthreads();
        if (s + 1 < 4) stage(s + 1, nxt);
        const bf16x8* fr = (const bf16x8*)cur;
        bf16x8 ah[4], al[4], bh[4], bl[4];
        #pragma unroll
        for (int mi = 0; mi < 4; ++mi) {
            ah[mi] = fr[(0 + wi * 4 + mi) * 64 + lane];
            al[mi] = fr[(8 + wi * 4 + mi) * 64 + lane];
        }
        #pragma unroll
        for (int nj = 0; nj < 4; ++nj) {
            bh[nj] = fr[(16 + wj * 4 + nj) * 64 + lane];
            bl[nj] = fr[(24 + wj * 4 + nj) * 64 + lane];
        }
        #pragma unroll
        for (int mi = 0; mi < 4; ++mi)
            #pragma unroll
            for (int nj = 0; nj < 4; ++nj) {
                acc[mi][nj] = __builtin_amdgcn_mfma_f32_16x16x32_bf16(
                    ah[mi], bh[nj], acc[mi][nj], 0, 0, 0);
                acc[mi][nj] = __builtin_amdgcn_mfma_f32_16x16x32_bf16(
                    ah[mi], bl[nj], acc[mi][nj], 0, 0, 0);
                acc[mi][nj] = __builtin_amdgcn_mfma_f32_16x16x32_bf16(
                    al[mi], bh[nj], acc[mi][nj], 0, 0, 0);
            }
    }

    // epilogue: bias + prelu -> hi/lo planes via LDS
    float bv[4], av[4];
    #pragma unroll
    for (int nj = 0; nj < 4; ++nj) {
        int col = wj * 64 + nj * 16 + laneL;
        bv[nj] = bias[col];
        av[nj] = prelu[col];
    }
    unsigned short* lp = &lds[0][0];
    __syncthreads();
    #pragma unroll
    for (int nj = 0; nj < 4; ++nj) {
        int col = wj * 64 + nj * 16 + laneL;
        #pragma unroll
        for (int mi = 0; mi < 4; ++mi)
            #pragma unroll
            for (int r = 0; r < 4; ++r) {
                int row = wi * 64 + mi * 16 + laneH * 4 + r;
                float v = acc[mi][nj][r] + bv[nj];
                v = v >= 0.f ? v : av[nj] * v;
                lp[row * 128 + col] = f2bf(v);
            }
    }
    __syncthreads();
    {
        const uint4* lsrc = (const uint4*)lp;
        #pragma unroll
        for (int it = 0; it < 8; ++it) {
            int idx = it * 256 + t;
            int row = idx >> 4, c = idx & 15;
            int m = m0 + row;
            if (m < M)
                ((uint4*)(C_hi + (size_t)m * 128))[c] = lsrc[idx];
        }
    }
    __syncthreads();
    #pragma unroll
    for (int nj = 0; nj < 4; ++nj) {
        int col = wj * 64 + nj * 16 + laneL;
        #pragma unroll
        for (int mi = 0; mi < 4; ++mi)
            #pragma unroll
            for (int r = 0; r < 4; ++r) {
                int row = wi * 64 + mi * 16 + laneH * 4 + r;
                float v = acc[mi][nj][r] + bv[nj];
                v = v >= 0.f ? v : av[nj] * v;
                unsigned short h = f2bf(v);
                lp[row * 128 + col] = f2bf(v - bf2f(h));
            }
    }
    __syncthreads();
    {
        const uint4* lsrc = (const uint4*)lp;
        #pragma unroll
        for (int it = 0; it < 8; ++it) {
            int idx = it * 256 + t;
            int row = idx >> 4, c = idx & 15;
            int m = m0 + row;
            if (m < M)
                ((uint4*)(C_lo + (size_t)m * 128))[c] = lsrc[idx];
        }
    }
}

// ---- pass A: per-block bin histogram, ROW-major (coalesced) output ----
__global__ __launch_bounds__(256) void k_hist(
    const int* __restrict__ ei, const int* __restrict__ et,
    int* __restrict__ cntmatT, int E, int N, int NBINS)
{
    __shared__ int hist[1024];
    const int t = threadIdx.x, blk = blockIdx.x;
    for (int i = t; i < NBINS; i += 256) hist[i] = 0;
    __syncthreads();
    #pragma unroll
    for (int j = 0; j < 8; ++j) {
        int e = blk * 2048 + j * 256 + t;
        if (e < E) atomicAdd(&hist[(et[e] * N + ei[E + e]) >> 8], 1);
    }
    __syncthreads();
    for (int i = t; i < NBINS; i += 256)
        cntmatT[(size_t)blk * NBINS + i] = hist[i];
}

// ---- LDS-tiled int transpose: dst[c*R + r] = src[r*C + c] ----
__global__ __launch_bounds__(256) void k_transpose(
    const int* __restrict__ src, int* __restrict__ dst, int R, int C)
{
    __shared__ int tile[32][33];
    int ctiles = (C + 31) >> 5;
    int bx = blockIdx.x % ctiles;
    int by = blockIdx.x / ctiles;
    int tc = threadIdx.x & 31, tr = threadIdx.x >> 5;
    int c0 = bx * 32, r0 = by * 32;
    #pragma unroll
    for (int i = 0; i < 32; i += 8) {
        int r = r0 + tr + i, c = c0 + tc;
        if (r < R && c < C) tile[tr + i][tc] = src[(size_t)r * C + c];
    }
    __syncthreads();
    #pragma unroll
    for (int i = 0; i < 32; i += 8) {
        int r = r0 + tc;
        int c = c0 + tr + i;
        if (r < R && c < C) dst[(size_t)c * R + r] = tile[tc][tr + i];
    }
}

// ---- weight split+transpose ----
struct WArgs {
    const float* W[8];
    unsigned short* hi[8];
    unsigned short* lo[8];
};
__global__ __launch_bounds__(256) void k_wsplit(WArgs a)
{
    int part = blockIdx.y;
    int idx = blockIdx.x * 256 + threadIdx.x;
    int n = idx >> 7, k = idx & 127;
    float v = a.W[part][(size_t)k * 128 + n];
    unsigned short h = f2bf(v);
    a.hi[part][(size_t)n * 128 + k] = h;
    a.lo[part][(size_t)n * 128 + k] = f2bf(v - bf2f(h));
}

// ---- scans over the bin-major count matrix (3-pass, no serial chains) ----
__global__ __launch_bounds__(256) void k_scan1(
    const int* __restrict__ src, int* __restrict__ dst,
    int* __restrict__ bsum, int n)
{
    __shared__ int s[256];
    int t = threadIdx.x;
    int i = blockIdx.x * 256 + t;
    int v = (i < n) ? src[i] : 0;
    s[t] = v;
    __syncthreads();
    #pragma unroll
    for (int d = 1; d < 256; d <<= 1) {
        int add = (t >= d) ? s[t - d] : 0;
        __syncthreads();
        s[t] += add;
        __syncthreads();
    }
    if (i < n) dst[i] = s[t] - v;
    if (t == 255) bsum[blockIdx.x] = s[255];
}

__global__ __launch_bounds__(1024) void k_scan2(int* __restrict__ bsum, int nb)
{
    __shared__ int s[1024];
    int t = threadIdx.x;
    int carry = 0;
    for (int base = 0; base < nb; base += 1024) {
        int i = base + t;
        int v = (i < nb) ? bsum[i] : 0;
        s[t] = v;
        __syncthreads();
        #pragma unroll
        for (int d = 1; d < 1024; d <<= 1) {
            int add = (t >= d) ? s[t - d] : 0;
            __syncthreads();
            s[t] += add;
            __syncthreads();
        }
        if (i < nb) bsum[i] = carry + s[t] - v;
        carry += s[1023];
        __syncthreads();
    }
}

__global__ __launch_bounds__(256) void k_scan3(
    int* __restrict__ dst, const int* __restrict__ bsum, int n)
{
    int i = blockIdx.x * 256 + threadIdx.x;
    if (i < n) dst[i] += bsum[blockIdx.x];
}

// ---- pass C: scatter edges into bin-contiguous ebuf (LDS cursors) ----
__global__ __launch_bounds__(256) void k_binscatter(
    const int* __restrict__ ei, const int* __restrict__ et,
    const int* __restrict__ cntscanT, int* __restrict__ ebuf,
    int E, int N, int NBINS)
{
    __shared__ int base[1024];
    const int t = threadIdx.x;
    const int blk = blockIdx.x;
    for (int i = t; i < NBINS; i += 256)
        base[i] = cntscanT[(size_t)blk * NBINS + i];
    __syncthreads();
    #pragma unroll
    for (int j = 0; j < 8; ++j) {
        int e = blk * 2048 + j * 256 + t;
        if (e < E) {
            unsigned src = (unsigned)ei[e];
            int seg = et[e] * N + ei[E + e];
            int pos = atomicAdd(&base[seg >> 8], 1);     // LDS atomic
            ebuf[pos] = (int)(((unsigned)(seg & 255) << 24) | src);
        }
    }
}

// ---- pass D: per-bin exact CSR (256 segs/bin, LDS count + scan) ----
__global__ __launch_bounds__(256) void k_bincsr(
    const int* __restrict__ cntscan, const int* __restrict__ ebuf,
    int* __restrict__ deg, int* __restrict__ off, int* __restrict__ esrc,
    int E, int nseg, int NBLK, int NBINS)
{
    __shared__ int cnt[256];
    __shared__ int pfx[256];
    __shared__ int cur[256];
    const int b = blockIdx.x;
    const int t = threadIdx.x;
    const int est = cntscan[(size_t)b * NBLK];
    const int een = (b + 1 < NBINS) ? cntscan[(size_t)(b + 1) * NBLK] : E;
    cnt[t] = 0;
    __syncthreads();
    for (int e = est + t; e < een; e += 256)
        atomicAdd(&cnt[((unsigned)ebuf[e]) >> 24], 1);
    __syncthreads();
    int v = cnt[t];
    pfx[t] = v;
    __syncthreads();
    #pragma unroll
    for (int d = 1; d < 256; d <<= 1) {
        int add = (t >= d) ? pfx[t - d] : 0;
        __syncthreads();
        pfx[t] += add;
        __syncthreads();
    }
    int o = est + pfx[t] - v;
    int seg = b * 256 + t;
    if (seg < nseg) { deg[seg] = v; off[seg] = o; }
    cur[t] = o;
    __syncthreads();
    for (int e = est + t; e < een; e += 256) {
        unsigned u = (unsigned)ebuf[e];
        int p = atomicAdd(&cur[u >> 24], 1);             // LDS atomic
        esrc[p] = (int)(u & 0xffffffu);
    }
}

// ---- mean aggregation, bf16 hi plane, quarter-wave rows ----
__global__ __launch_bounds__(256) void k_gather(
    const unsigned short* __restrict__ h_hi,
    const int* __restrict__ esrc,
    const int* __restrict__ off, const int* __restrict__ deg,
    unsigned short* __restrict__ a_hi, int nseg)
{
    int i = blockIdx.x * 8 + (threadIdx.x >> 5);
    if (i >= nseg) return;
    int l32 = threadIdx.x & 31;
    int q = l32 >> 4;
    int l16 = l32 & 15;
    int cnt = deg[i], st = off[i];
    const uint4* hp = (const uint4*)h_hi;
    float a0 = 0.f, a1 = 0.f, a2 = 0.f, a3 = 0.f;
    float a4 = 0.f, a5 = 0.f, a6 = 0.f, a7 = 0.f;
    int e = q;
    for (; e + 6 < cnt; e += 8) {
        int i0 = esrc[st + e + 0];
        int i1 = esrc[st + e + 2];
        int i2 = esrc[st + e + 4];
        int i3 = esrc[st + e + 6];
        uint4 u0 = hp[(size_t)i0 * 16 + l16];
        uint4 u1 = hp[(size_t)i1 * 16 + l16];
        uint4 u2 = hp[(size_t)i2 * 16 + l16];
        uint4 u3 = hp[(size_t)i3 * 16 + l16];
        a0 += lo16f(u0.x); a1 += hi16f(u0.x); a2 += lo16f(u0.y); a3 += hi16f(u0.y);
        a4 += lo16f(u0.z); a5 += hi16f(u0.z); a6 += lo16f(u0.w); a7 += hi16f(u0.w);
        a0 += lo16f(u1.x); a1 += hi16f(u1.x); a2 += lo16f(u1.y); a3 += hi16f(u1.y);
        a4 += lo16f(u1.z); a5 += hi16f(u1.z); a6 += lo16f(u1.w); a7 += hi16f(u1.w);
        a0 += lo16f(u2.x); a1 += hi16f(u2.x); a2 += lo16f(u2.y); a3 += hi16f(u2.y);
        a4 += lo16f(u2.z); a5 += hi16f(u2.z); a6 += lo16f(u2.w); a7 += hi16f(u2.w);
        a0 += lo16f(u3.x); a1 += hi16f(u3.x); a2 += lo16f(u3.y); a3 += hi16f(u3.y);
        a4 += lo16f(u3.z); a5 += hi16f(u3.z); a6 += lo16f(u3.w); a7 += hi16f(u3.w);
    }
    for (; e < cnt; e += 2) {
        uint4 u = hp[(size_t)esrc[st + e] * 16 + l16];
        a0 += lo16f(u.x); a1 += hi16f(u.x); a2 += lo16f(u.y); a3 += hi16f(u.y);
        a4 += lo16f(u.z); a5 += hi16f(u.z); a6 += lo16f(u.w); a7 += hi16f(u.w);
    }
    a0 += __shfl_xor(a0, 16, 64);
    a1 += __shfl_xor(a1, 16, 64);
    a2 += __shfl_xor(a2, 16, 64);
    a3 += __shfl_xor(a3, 16, 64);
    a4 += __shfl_xor(a4, 16, 64);
    a5 += __shfl_xor(a5, 16, 64);
    a6 += __shfl_xor(a6, 16, 64);
    a7 += __shfl_xor(a7, 16, 64);
    if (q == 0) {
        float inv = 1.0f / (float)(cnt > 1 ? cnt : 1);
        uint4 o;
        o.x = (unsigned int)f2bf(a0 * inv) | ((unsigned int)f2bf(a1 * inv) << 16);
        o.y = (unsigned int)f2bf(a2 * inv) | ((unsigned int)f2bf(a3 * inv) << 16);
        o.z = (unsigned int)f2bf(a4 * inv) | ((unsigned int)f2bf(a5 * inv) << 16);
        o.w = (unsigned int)f2bf(a6 * inv) | ((unsigned int)f2bf(a7 * inv) << 16);
        ((uint4*)a_hi)[(size_t)i * 16 + l16] = o;
    }
}

// ---- pipelined split-bf16 MFMA GEMM ----
struct GArgs {
    const unsigned short* A_hi[3];
    const unsigned short* A_lo[3];
    const unsigned short* B_hi[3];   // transposed [n][k]
    const unsigned short* B_lo[3];
    int alo[3];
    int blo[3];
    const float* bias;
    const float* prelu;
    float* Cf;                       // if non-null: fp32 output
    unsigned short* C_hi;
    unsigned short* C_lo;
    int M;
    int P;
};

__global__ __launch_bounds__(256) void k_mgemm(GArgs g)
{
    __shared__ unsigned short lds[2][32 * 512];   // 2 x 32 KB
    const int t = threadIdx.x;
    const int w = t >> 6, lane = t & 63;
    const int laneL = lane & 15, laneH = lane >> 4;
    const int wi = w >> 1, wj = w & 1;
    const int m0 = blockIdx.x * 128;
    const int Mm1 = g.M - 1;
    const int S = g.P * 4;

    f32x4 acc[4][4];
    #pragma unroll
    for (int a = 0; a < 4; ++a)
        #pragma unroll
        for (int b = 0; b < 4; ++b)
            acc[a][b] = (f32x4){0.f, 0.f, 0.f, 0.f};

    auto stage = [&](int s, unsigned short* buf) {
        int p = s >> 2, koff = (s & 3) * 32;
        const unsigned short* tp[4];
        tp[0] = g.A_hi[p];
        tp[1] = g.alo[p] ? g.A_lo[p] : nullptr;
        tp[2] = g.B_hi[p];
        tp[3] = g.blo[p] ? g.B_lo[p] : nullptr;
        #pragma unroll
        for (int c = 0; c < 8; ++c) {
            int chunk = w + c * 4;            // 0..31
            int slot = chunk >> 3, j = chunk & 7;
            const unsigned short* plane = tp[slot];
            if (!plane) continue;
            int rc = j * 16 + laneL;
            int row = (slot < 2) ? (m0 + rc <= Mm1 ? m0 + rc : Mm1) : rc;
            const unsigned short* gp = plane + (size_t)row * 128 + koff + laneH * 8;
            gload_lds16(gp, &buf[(slot * 8 + j) * 512]);
        }
    };

    stage(0, lds[0]);
    for (int s = 0; s < S; ++s) {
        unsigned short* cur = lds[s & 1];
        unsigned short* nxt = lds[(s & 1) ^ 1];
        __syncthreads();                      // drains stage(s); frees nxt
        if (s + 1 < S) stage(s + 1, nxt);     // overlaps with compute below
        int p = s >> 2;
        const bool hasAlo = g.alo[p] != 0;
        const bool hasBlo = g.blo[p] != 0;
        const bf16x8* fr = (const bf16x8*)cur;
        bf16x8 ah[4], al[4], bh[4], bl[4];
        #pragma unroll
        for (int mi = 0; mi < 4; ++mi)
            ah[mi] = fr[(0 + wi * 4 + mi) * 64 + lane];
        if (hasAlo) {
            #pragma unroll
            for (int mi = 0; mi < 4; ++mi)
                al[mi] = fr[(8 + wi * 4 + mi) * 64 + lane];
        }
        #pragma unroll
        for (int nj = 0; nj < 4; ++nj)
            bh[nj] = fr[(16 + wj * 4 + nj) * 64 + lane];
        if (hasBlo) {
            #pragma unroll
            for (int nj = 0; nj < 4; ++nj)
                bl[nj] = fr[(24 + wj * 4 + nj) * 64 + lane];
        }
        #pragma unroll
        for (int mi = 0; mi < 4; ++mi)
            #pragma unroll
            for (int nj = 0; nj < 4; ++nj) {
                acc[mi][nj] = __builtin_amdgcn_mfma_f32_16x16x32_bf16(
                    ah[mi], bh[nj], acc[mi][nj], 0, 0, 0);
                if (hasBlo)
                    acc[mi][nj] = __builtin_amdgcn_mfma_f32_16x16x32_bf16(
                        ah[mi], bl[nj], acc[mi][nj], 0, 0, 0);
                if (hasAlo)
                    acc[mi][nj] = __builtin_amdgcn_mfma_f32_16x16x32_bf16(
                        al[mi], bh[nj], acc[mi][nj], 0, 0, 0);
            }
    }

    // ---- epilogue: acc -> LDS (C layout) -> coalesced stores ----
    const bool hasPrelu = (g.prelu != nullptr);
    float bv[4], av[4];
    #pragma unroll
    for (int nj = 0; nj < 4; ++nj) {
        int col = wj * 64 + nj * 16 + laneL;
        bv[nj] = g.bias[col];
        av[nj] = hasPrelu ? g.prelu[col] : 0.f;
    }

    if (g.Cf) {
        float* lf = (float*)&lds[0][0];       // 128x128 f32 = 64 KB
        __syncthreads();
        #pragma unroll
        for (int nj = 0; nj < 4; ++nj) {
            int col = wj * 64 + nj * 16 + laneL;
            #pragma unroll
            for (int mi = 0; mi < 4; ++mi)
                #pragma unroll
                for (int r = 0; r < 4; ++r) {
                    int row = wi * 64 + mi * 16 + laneH * 4 + r;
                    float v = acc[mi][nj][r] + bv[nj];
                    lf[row * 128 + col] = v;
                }
        }
        __syncthreads();
        const uint4* lsrc = (const uint4*)lf;
        #pragma unroll
        for (int it = 0; it < 16; ++it) {
            int idx = it * 256 + t;          // 4096 uint4
            int row = idx >> 5, c = idx & 31;
            int m = m0 + row;
            if (m < g.M)
                ((uint4*)(g.Cf + (size_t)m * 128))[c] = lsrc[idx];
        }
    } else {
        unsigned short* lp = &lds[0][0];     // 128x128 ushort = 32 KB
        // hi pass
        __syncthreads();
        #pragma unroll
        for (int nj = 0; nj < 4; ++nj) {
            int col = wj * 64 + nj * 16 + laneL;
            #pragma unroll
            for (int mi = 0; mi < 4; ++mi)
                #pragma unroll
                for (int r = 0; r < 4; ++r) {
                    int row = wi * 64 + mi * 16 + laneH * 4 + r;
                    float v = acc[mi][nj][r] + bv[nj];
                    if (hasPrelu) v = v >= 0.f ? v : av[nj] * v;
                    lp[row * 128 + col] = f2bf(v);
                }
        }
        __syncthreads();
        {
            const uint4* lsrc = (const uint4*)lp;
            #pragma unroll
            for (int it = 0; it < 8; ++it) {
                int idx = it * 256 + t;      // 2048 uint4
                int row = idx >> 4, c = idx & 15;
                int m = m0 + row;
                if (m < g.M)
                    ((uint4*)(g.C_hi + (size_t)m * 128))[c] = lsrc[idx];
            }
        }
        // lo pass
        __syncthreads();
        #pragma unroll
        for (int nj = 0; nj < 4; ++nj) {
            int col = wj * 64 + nj * 16 + laneL;
            #pragma unroll
            for (int mi = 0; mi < 4; ++mi)
                #pragma unroll
                for (int r = 0; r < 4; ++r) {
                    int row = wi * 64 + mi * 16 + laneH * 4 + r;
                    float v = acc[mi][nj][r] + bv[nj];
                    if (hasPrelu) v = v >= 0.f ? v : av[nj] * v;
                    unsigned short h = f2bf(v);
                    lp[row * 128 + col] = f2bf(v - bf2f(h));
                }
        }
        __syncthreads();
        {
            const uint4* lsrc = (const uint4*)lp;
            #pragma unroll
            for (int it = 0; it < 8; ++it) {
                int idx = it * 256 + t;
                int row = idx >> 4, c = idx & 15;
                int m = m0 + row;
                if (m < g.M)
                    ((uint4*)(g.C_lo + (size_t)m * 128))[c] = lsrc[idx];
            }
        }
    }
}

extern "C" void kernel_launch(void* const* d_in, const int* in_sizes, int n_in,
                              void* d_out, int out_size, void* d_ws, size_t ws_size,
                              hipStream_t stream) {
    const float* x      = (const float*)d_in[0];
    const int*   ei     = (const int*)d_in[1];
    const int*   et     = (const int*)d_in[2];
    const float* Wnum   = (const float*)d_in[3];
    const float* bnum   = (const float*)d_in[4];
    const float* Wcat   = (const float*)d_in[5];
    const float* bcat   = (const float*)d_in[6];
    const float* Win    = (const float*)d_in[7];
    const float* bin    = (const float*)d_in[8];
    const float* pa     = (const float*)d_in[9];
    const float* Wrel1  = (const float*)d_in[10];
    const float* Wroot1 = (const float*)d_in[11];
    const float* brg1   = (const float*)d_in[12];
    const float* Wrel2  = (const float*)d_in[13];
    const float* Wroot2 = (const float*)d_in[14];
    const float* brg2   = (const float*)d_in[15];
    const float* Wcls   = (const float*)d_in[16];
    const float* bcls   = (const float*)d_in[17];
    float* out = (float*)d_out;

    const int N = in_sizes[0] / 8;
    const int E = in_sizes[1] / 2;
    const int nseg = 2 * N;
    const size_t NH = (size_t)N * 128;

    const int NBLK  = (E + 2047) / 2048;        // edge blocks (782)
    const int NBINS = (nseg + 255) / 256;       // coarse bins (782)
    const long long L = (long long)NBINS * NBLK;

    char* w = (char*)d_ws;
    unsigned short* h0_hi = (unsigned short*)w;  w += NH * 2;
    unsigned short* h0_lo = (unsigned short*)w;  w += NH * 2;
    unsigned short* agg_hi = (unsigned short*)w; w += 2 * NH * 2;
    int* deg      = (int*)w;  w += (size_t)nseg * 4;
    int* off      = (int*)w;  w += (size_t)nseg * 4;
    int* cntmatT  = (int*)w;  w += (size_t)L * 4;   // [blk][bin]
    int* cntmat   = (int*)w;  w += (size_t)L * 4;   // [bin][blk]
    int* cntscan  = (int*)w;  w += (size_t)L * 4;   // [bin][blk] scanned
    int* cntscanT = (int*)w;  w += (size_t)L * 4;   // [blk][bin] scanned
    int* esrc     = (int*)w;  w += (size_t)E * 4;
    int* bsum     = (int*)w;  w += 4096 * 4;
    unsigned short* wplanes = (unsigned short*)w;  w += 8 * 2 * 16384 * 2;

    unsigned short* h1_hi = (unsigned short*)d_out;
    unsigned short* h1_lo = h1_hi + NH;
    unsigned short* h2_hi = h0_hi;
    unsigned short* h2_lo = h0_lo;
    int* ebuf = (int*)d_out;   // E ints; dead before h1 is written (layer-1 GEMM)

    unsigned short* whi[8];
    unsigned short* wlo[8];
    for (int i = 0; i < 8; ++i) {
        whi[i] = wplanes + (size_t)i * 2 * 16384;
        wlo[i] = whi[i] + 16384;
    }

    {
        WArgs a;
        a.W[0] = Win;   a.W[1] = Wroot1; a.W[2] = Wrel1; a.W[3] = Wrel1 + 16384;
        a.W[4] = Wroot2; a.W[5] = Wrel2; a.W[6] = Wrel2 + 16384; a.W[7] = Wcls;
        for (int i = 0; i < 8; ++i) { a.hi[i] = whi[i]; a.lo[i] = wlo[i]; }
        k_wsplit<<<dim3(64, 8), 256, 0, stream>>>(a);
    }

    const int gm = (N + 127) / 128;
    const int gg = (nseg + 7) / 8;

    // CSR pipeline
    k_hist<<<NBLK, 256, 0, stream>>>(ei, et, cntmatT, E, N, NBINS);

    const int rt = (NBLK + 31) / 32, ct = (NBINS + 31) / 32;
    k_transpose<<<rt * ct, 256, 0, stream>>>(cntmatT, cntmat, NBLK, NBINS);

    const int nb1 = (int)((L + 255) / 256);
    k_scan1<<<nb1, 256, 0, stream>>>(cntmat, cntscan, bsum, (int)L);
    k_scan2<<<1, 1024, 0, stream>>>(bsum, nb1);
    k_scan3<<<nb1, 256, 0, stream>>>(cntscan, bsum, (int)L);

    k_transpose<<<ct * rt, 256, 0, stream>>>(cntscan, cntscanT, NBINS, NBLK);

    k_binscatter<<<NBLK, 256, 0, stream>>>(ei, et, cntscanT, ebuf, E, N, NBINS);
    k_bincsr<<<NBINS, 256, 0, stream>>>(cntscan, ebuf, deg, off, esrc, E, nseg, NBLK, NBINS);

    // fused embed GEMM (x -> h0 planes)
    k_egemm<<<gm, 256, 0, stream>>>(x, Wnum, bnum, Wcat, bcat,
                                    whi[0], wlo[0], bin, pa,
                                    h0_hi, h0_lo, N);

    // layer 1
    k_gather<<<gg, 256, 0, stream>>>(h0_hi, esrc, off, deg, agg_hi, nseg);
    {
        GArgs g = {};
        g.A_hi[0] = h0_hi;       g.A_lo[0] = h0_lo;  g.alo[0] = 1; g.blo[0] = 1;
        g.A_hi[1] = agg_hi;      g.alo[1] = 0;       g.blo[1] = 0;
        g.A_hi[2] = agg_hi + NH; g.alo[2] = 0;       g.blo[2] = 0;
        g.B_hi[0] = whi[1]; g.B_lo[0] = wlo[1];
        g.B_hi[1] = whi[2]; g.B_lo[1] = wlo[2];
        g.B_hi[2] = whi[3]; g.B_lo[2] = wlo[3];
        g.bias = brg1; g.prelu = nullptr;
        g.Cf = nullptr; g.C_hi = h1_hi; g.C_lo = h1_lo;
        g.M = N; g.P = 3;
        k_mgemm<<<gm, 256, 0, stream>>>(g);
    }
    // layer 2
    k_gather<<<gg, 256, 0, stream>>>(h1_hi, esrc, off, deg, agg_hi, nseg);
    {
        GArgs g = {};
        g.A_hi[0] = h1_hi;       g.A_lo[0] = h1_lo;  g.alo[0] = 1; g.blo[0] = 1;
        g.A_hi[1] = agg_hi;      g.alo[1] = 0;       g.blo[1] = 0;
        g.A_hi[2] = agg_hi + NH; g.alo[2] = 0;       g.blo[2] = 0;
        g.B_hi[0] = whi[4]; g.B_lo[0] = wlo[4];
        g.B_hi[1] = whi[5]; g.B_lo[1] = wlo[5];
        g.B_hi[2] = whi[6]; g.B_lo[2] = wlo[6];
        g.bias = brg2; g.prelu = nullptr;
        g.Cf = nullptr; g.C_hi = h2_hi; g.C_lo = h2_lo;
        g.M = N; g.P = 3;
        k_mgemm<<<gm, 256, 0, stream>>>(g);
    }
    // classifier
    {
        GArgs g = {};
        g.A_hi[0] = h2_hi; g.A_lo[0] = h2_lo; g.alo[0] = 1; g.blo[0] = 1;
        g.B_hi[0] = whi[7]; g.B_lo[0] = wlo[7];
        g.bias = bcls; g.prelu = nullptr;
        g.Cf = out; g.C_hi = nullptr; g.C_lo = nullptr;
        g.M = N; g.P = 1;
        k_mgemm<<<gm, 256, 0, stream>>>(g);
    }
}

// Round 7
// 434.838 us; speedup vs baseline: 1.3976x; 1.0917x over previous
//
#include <hip/hip_runtime.h>
#include <cstdint>

// ---------------------------------------------------------------------------
// BotRGCN round 14: fuse classifier into layer-2 GEMM + epilogue/CSR trims.
//  - k_mgemm fused-cls tail: layer-2 block writes its h2 tile as SWIZZLED
//    bf16 hi/lo planes into LDS (XOR (row&7)<<4 -> conflict-free ds_read_b128
//    A-frags), cls B-frags load from global (L2-resident 32KB planes),
//    192 MFMA/wave, fp32 out. Kills the 102 MB h2 HBM round-trip + 1 launch.
//    Buffer rotation (zero extra ws): ebuf->d_out, h0->d_out (after bincsr),
//    h1->ws, out->d_out (h0 dead by then).
//  - Single-pass bf16 epilogues (hi->lds[0], lo->lds[1], 2 syncs not 4).
//  - CSR: scan3 folded into transpose2(+bsum) and bincsr's scalar reads;
//    wsplit+hist merged into one launch; edge blocks 2048->4096 (NBLK 391).
//  k_gather untouched (at 6.3 TB/s effective roofline, 2x65 us).
// ---------------------------------------------------------------------------

typedef short bf16x8 __attribute__((ext_vector_type(8)));
typedef float f32x4  __attribute__((ext_vector_type(4)));

__device__ __forceinline__ unsigned short f2bf(float f) {
    unsigned int u = __builtin_bit_cast(unsigned int, f);
    u += 0x7fff + ((u >> 16) & 1);          // RNE
    return (unsigned short)(u >> 16);
}
__device__ __forceinline__ float bf2f(unsigned short h) {
    unsigned int u = ((unsigned int)h) << 16;
    return __builtin_bit_cast(float, u);
}
__device__ __forceinline__ float lo16f(unsigned int u) {
    return __builtin_bit_cast(float, u << 16);
}
__device__ __forceinline__ float hi16f(unsigned int u) {
    return __builtin_bit_cast(float, u & 0xffff0000u);
}

__device__ __forceinline__ void gload_lds16(const void* g, void* l) {
    __builtin_amdgcn_global_load_lds(
        (const __attribute__((address_space(1))) void*)g,
        (__attribute__((address_space(3))) void*)l, 16, 0, 0);
}

// ---- fused embed GEMM: A computed from x into LDS, B gloaded ----
__global__ __launch_bounds__(256) void k_egemm(
    const float* __restrict__ x,
    const float* __restrict__ Wnum, const float* __restrict__ bnum,
    const float* __restrict__ Wcat, const float* __restrict__ bcat,
    const unsigned short* __restrict__ Bhi, const unsigned short* __restrict__ Blo,
    const float* __restrict__ bias, const float* __restrict__ prelu,
    unsigned short* __restrict__ C_hi, unsigned short* __restrict__ C_lo, int M)
{
    __shared__ unsigned short lds[2][32 * 512];   // 2 x 32 KB
    const int t = threadIdx.x;
    const int w = t >> 6, lane = t & 63;
    const int laneL = lane & 15, laneH = lane >> 4;
    const int wi = w >> 1, wj = w & 1;
    const int m0 = blockIdx.x * 128;
    const int Mm1 = M - 1;

    f32x4 acc[4][4];
    #pragma unroll
    for (int a = 0; a < 4; ++a)
        #pragma unroll
        for (int b = 0; b < 4; ++b)
            acc[a][b] = (f32x4){0.f, 0.f, 0.f, 0.f};

    auto stage = [&](int s, unsigned short* buf) {
        int koff = s * 32;
        int k8 = koff + laneH * 8;            // 8 dims, never straddles 64
        #pragma unroll
        for (int c = 0; c < 2; ++c) {
            int j = w + c * 4;                // A chunk j in 0..7
            int rc = j * 16 + laneL;
            int row = (m0 + rc <= Mm1) ? (m0 + rc) : Mm1;
            const float4* xr = (const float4*)(x + (size_t)row * 8);
            float4 X0 = xr[0], X1 = xr[1];
            float a[8];
            if (k8 < 64) {
                const float4* bp = (const float4*)(bnum + k8);
                float4 b0 = bp[0], b1 = bp[1];
                a[0]=b0.x; a[1]=b0.y; a[2]=b0.z; a[3]=b0.w;
                a[4]=b1.x; a[5]=b1.y; a[6]=b1.z; a[7]=b1.w;
                float xs0 = X0.x, xs1 = X0.y, xs2 = X0.z, xs3 = X0.w, xs4 = X1.x;
                const float* wb = Wnum + k8;
                #pragma unroll
                for (int p = 0; p < 5; ++p) {
                    float xp = p==0?xs0 : p==1?xs1 : p==2?xs2 : p==3?xs3 : xs4;
                    const float4* wp = (const float4*)(wb + p * 64);
                    float4 w0 = wp[0], w1 = wp[1];
                    a[0]+=xp*w0.x; a[1]+=xp*w0.y; a[2]+=xp*w0.z; a[3]+=xp*w0.w;
                    a[4]+=xp*w1.x; a[5]+=xp*w1.y; a[6]+=xp*w1.z; a[7]+=xp*w1.w;
                }
            } else {
                int kk = k8 - 64;
                const float4* bp = (const float4*)(bcat + kk);
                float4 b0 = bp[0], b1 = bp[1];
                a[0]=b0.x; a[1]=b0.y; a[2]=b0.z; a[3]=b0.w;
                a[4]=b1.x; a[5]=b1.y; a[6]=b1.z; a[7]=b1.w;
                float xs0 = X1.y, xs1 = X1.z, xs2 = X1.w;
                const float* wb = Wcat + kk;
                #pragma unroll
                for (int p = 0; p < 3; ++p) {
                    float xp = p==0?xs0 : p==1?xs1 : xs2;
                    const float4* wp = (const float4*)(wb + p * 64);
                    float4 w0 = wp[0], w1 = wp[1];
                    a[0]+=xp*w0.x; a[1]+=xp*w0.y; a[2]+=xp*w0.z; a[3]+=xp*w0.w;
                    a[4]+=xp*w1.x; a[5]+=xp*w1.y; a[6]+=xp*w1.z; a[7]+=xp*w1.w;
                }
            }
            unsigned hw[4], lw[4];
            #pragma unroll
            for (int q = 0; q < 4; ++q) {
                float v0 = a[2*q]   >= 0.f ? a[2*q]   : 0.01f * a[2*q];
                float v1 = a[2*q+1] >= 0.f ? a[2*q+1] : 0.01f * a[2*q+1];
                unsigned short h0 = f2bf(v0), h1 = f2bf(v1);
                unsigned short l0 = f2bf(v0 - bf2f(h0)), l1 = f2bf(v1 - bf2f(h1));
                hw[q] = (unsigned)h0 | ((unsigned)h1 << 16);
                lw[q] = (unsigned)l0 | ((unsigned)l1 << 16);
            }
            uint4 ho, lo_;
            ho.x=hw[0]; ho.y=hw[1]; ho.z=hw[2]; ho.w=hw[3];
            lo_.x=lw[0]; lo_.y=lw[1]; lo_.z=lw[2]; lo_.w=lw[3];
            *(uint4*)&buf[(0 * 8 + j) * 512 + lane * 8] = ho;
            *(uint4*)&buf[(1 * 8 + j) * 512 + lane * 8] = lo_;
        }
        #pragma unroll
        for (int c = 4; c < 8; ++c) {
            int chunk = w + c * 4;            // 16..31 -> slots 2,3
            int slot = chunk >> 3, j = chunk & 7;
            const unsigned short* plane = (slot == 2) ? Bhi : Blo;
            int rc = j * 16 + laneL;
            const unsigned short* gp = plane + (size_t)rc * 128 + koff + laneH * 8;
            gload_lds16(gp, &buf[(slot * 8 + j) * 512]);
        }
    };

    stage(0, lds[0]);
    for (int s = 0; s < 4; ++s) {
        unsigned short* cur = lds[s & 1];
        unsigned short* nxt = lds[(s & 1) ^ 1];
        __syncthreads();
        if (s + 1 < 4) stage(s + 1, nxt);
        const bf16x8* fr = (const bf16x8*)cur;
        bf16x8 ah[4], al[4], bh[4], bl[4];
        #pragma unroll
        for (int mi = 0; mi < 4; ++mi) {
            ah[mi] = fr[(0 + wi * 4 + mi) * 64 + lane];
            al[mi] = fr[(8 + wi * 4 + mi) * 64 + lane];
        }
        #pragma unroll
        for (int nj = 0; nj < 4; ++nj) {
            bh[nj] = fr[(16 + wj * 4 + nj) * 64 + lane];
            bl[nj] = fr[(24 + wj * 4 + nj) * 64 + lane];
        }
        #pragma unroll
        for (int mi = 0; mi < 4; ++mi)
            #pragma unroll
            for (int nj = 0; nj < 4; ++nj) {
                acc[mi][nj] = __builtin_amdgcn_mfma_f32_16x16x32_bf16(
                    ah[mi], bh[nj], acc[mi][nj], 0, 0, 0);
                acc[mi][nj] = __builtin_amdgcn_mfma_f32_16x16x32_bf16(
                    ah[mi], bl[nj], acc[mi][nj], 0, 0, 0);
                acc[mi][nj] = __builtin_amdgcn_mfma_f32_16x16x32_bf16(
                    al[mi], bh[nj], acc[mi][nj], 0, 0, 0);
            }
    }

    // single-pass epilogue: hi -> lds[0], lo -> lds[1]
    float bv[4], av[4];
    #pragma unroll
    for (int nj = 0; nj < 4; ++nj) {
        int col = wj * 64 + nj * 16 + laneL;
        bv[nj] = bias[col];
        av[nj] = prelu[col];
    }
    unsigned short* lph = &lds[0][0];
    unsigned short* lpl = &lds[1][0];
    __syncthreads();
    #pragma unroll
    for (int nj = 0; nj < 4; ++nj) {
        int col = wj * 64 + nj * 16 + laneL;
        #pragma unroll
        for (int mi = 0; mi < 4; ++mi)
            #pragma unroll
            for (int r = 0; r < 4; ++r) {
                int row = wi * 64 + mi * 16 + laneH * 4 + r;
                float v = acc[mi][nj][r] + bv[nj];
                v = v >= 0.f ? v : av[nj] * v;
                unsigned short h = f2bf(v);
                lph[row * 128 + col] = h;
                lpl[row * 128 + col] = f2bf(v - bf2f(h));
            }
    }
    __syncthreads();
    {
        const uint4* sh = (const uint4*)lph;
        const uint4* sl = (const uint4*)lpl;
        #pragma unroll
        for (int it = 0; it < 8; ++it) {
            int idx = it * 256 + t;
            int row = idx >> 4, c = idx & 15;
            int m = m0 + row;
            if (m < M) {
                ((uint4*)(C_hi + (size_t)m * 128))[c] = sh[idx];
                ((uint4*)(C_lo + (size_t)m * 128))[c] = sl[idx];
            }
        }
    }
}

// ---- merged weight split + edge bin histogram ----
struct WHArgs {
    const float* W[8];
    unsigned short* hi[8];
    unsigned short* lo[8];
    const int* ei;
    const int* et;
    int* cntmatT;     // [blk][bin], coalesced rows
    int E;
    int N;
    int NBINS;
};
__global__ __launch_bounds__(256) void k_wsplit_hist(WHArgs a)
{
    __shared__ int hist[1024];
    const int t = threadIdx.x;
    const int b = blockIdx.x;
    if (b < 512) {
        int part = b >> 6;
        int idx = (b & 63) * 256 + t;
        int n = idx >> 7, k = idx & 127;
        float v = a.W[part][(size_t)k * 128 + n];
        unsigned short h = f2bf(v);
        a.hi[part][(size_t)n * 128 + k] = h;
        a.lo[part][(size_t)n * 128 + k] = f2bf(v - bf2f(h));
        return;
    }
    const int blk = b - 512;
    for (int i = t; i < a.NBINS; i += 256) hist[i] = 0;
    __syncthreads();
    #pragma unroll
    for (int j = 0; j < 16; ++j) {
        int e = blk * 4096 + j * 256 + t;
        if (e < a.E) atomicAdd(&hist[(a.et[e] * a.N + a.ei[a.E + e]) >> 8], 1);
    }
    __syncthreads();
    for (int i = t; i < a.NBINS; i += 256)
        a.cntmatT[(size_t)blk * a.NBINS + i] = hist[i];
}

// ---- LDS-tiled int transpose: dst[c*R + r] = src[r*C + c] ----
__global__ __launch_bounds__(256) void k_transpose(
    const int* __restrict__ src, int* __restrict__ dst, int R, int C)
{
    __shared__ int tile[32][33];
    int ctiles = (C + 31) >> 5;
    int bx = blockIdx.x % ctiles;
    int by = blockIdx.x / ctiles;
    int tc = threadIdx.x & 31, tr = threadIdx.x >> 5;
    int c0 = bx * 32, r0 = by * 32;
    #pragma unroll
    for (int i = 0; i < 32; i += 8) {
        int r = r0 + tr + i, c = c0 + tc;
        if (r < R && c < C) tile[tr + i][tc] = src[(size_t)r * C + c];
    }
    __syncthreads();
    #pragma unroll
    for (int i = 0; i < 32; i += 8) {
        int r = r0 + tc;
        int c = c0 + tr + i;
        if (r < R && c < C) dst[(size_t)c * R + r] = tile[tc][tr + i];
    }
}

// ---- transpose + bsum add (replaces scan3 for the T side) ----
__global__ __launch_bounds__(256) void k_transpose_add(
    const int* __restrict__ src, int* __restrict__ dst,
    const int* __restrict__ bsum, int R, int C)
{
    __shared__ int tile[32][33];
    int ctiles = (C + 31) >> 5;
    int bx = blockIdx.x % ctiles;
    int by = blockIdx.x / ctiles;
    int tc = threadIdx.x & 31, tr = threadIdx.x >> 5;
    int c0 = bx * 32, r0 = by * 32;
    #pragma unroll
    for (int i = 0; i < 32; i += 8) {
        int r = r0 + tr + i, c = c0 + tc;
        if (r < R && c < C) {
            size_t idx = (size_t)r * C + c;
            tile[tr + i][tc] = src[idx] + bsum[idx >> 8];
        }
    }
    __syncthreads();
    #pragma unroll
    for (int i = 0; i < 32; i += 8) {
        int r = r0 + tc;
        int c = c0 + tr + i;
        if (r < R && c < C) dst[(size_t)c * R + r] = tile[tc][tr + i];
    }
}

// ---- scan chain over the bin-major count matrix ----
__global__ __launch_bounds__(256) void k_scan1(
    const int* __restrict__ src, int* __restrict__ dst,
    int* __restrict__ bsum, int n)
{
    __shared__ int s[256];
    int t = threadIdx.x;
    int i = blockIdx.x * 256 + t;
    int v = (i < n) ? src[i] : 0;
    s[t] = v;
    __syncthreads();
    #pragma unroll
    for (int d = 1; d < 256; d <<= 1) {
        int add = (t >= d) ? s[t - d] : 0;
        __syncthreads();
        s[t] += add;
        __syncthreads();
    }
    if (i < n) dst[i] = s[t] - v;
    if (t == 255) bsum[blockIdx.x] = s[255];
}

__global__ __launch_bounds__(1024) void k_scan2(int* __restrict__ bsum, int nb)
{
    __shared__ int s[1024];
    int t = threadIdx.x;
    int carry = 0;
    for (int base = 0; base < nb; base += 1024) {
        int i = base + t;
        int v = (i < nb) ? bsum[i] : 0;
        s[t] = v;
        __syncthreads();
        #pragma unroll
        for (int d = 1; d < 1024; d <<= 1) {
            int add = (t >= d) ? s[t - d] : 0;
            __syncthreads();
            s[t] += add;
            __syncthreads();
        }
        if (i < nb) bsum[i] = carry + s[t] - v;
        carry += s[1023];
        __syncthreads();
    }
}

// ---- pass C: scatter edges into bin-contiguous ebuf (LDS cursors) ----
__global__ __launch_bounds__(256) void k_binscatter(
    const int* __restrict__ ei, const int* __restrict__ et,
    const int* __restrict__ cntscanT, int* __restrict__ ebuf,
    int E, int N, int NBINS)
{
    __shared__ int base[1024];
    const int t = threadIdx.x;
    const int blk = blockIdx.x;
    for (int i = t; i < NBINS; i += 256)
        base[i] = cntscanT[(size_t)blk * NBINS + i];
    __syncthreads();
    #pragma unroll
    for (int j = 0; j < 16; ++j) {
        int e = blk * 4096 + j * 256 + t;
        if (e < E) {
            unsigned src = (unsigned)ei[e];
            int seg = et[e] * N + ei[E + e];
            int pos = atomicAdd(&base[seg >> 8], 1);     // LDS atomic
            ebuf[pos] = (int)(((unsigned)(seg & 255) << 24) | src);
        }
    }
}

// ---- pass D: per-bin exact CSR (256 segs/bin, LDS count + scan) ----
__global__ __launch_bounds__(256) void k_bincsr(
    const int* __restrict__ cntscan, const int* __restrict__ bsum,
    const int* __restrict__ ebuf,
    int* __restrict__ deg, int* __restrict__ off, int* __restrict__ esrc,
    int E, int nseg, int NBLK, int NBINS)
{
    __shared__ int cnt[256];
    __shared__ int pfx[256];
    __shared__ int cur[256];
    const int b = blockIdx.x;
    const int t = threadIdx.x;
    size_t i0 = (size_t)b * NBLK;
    const int est = cntscan[i0] + bsum[i0 >> 8];
    int een = E;
    if (b + 1 < NBINS) {
        size_t i1 = (size_t)(b + 1) * NBLK;
        een = cntscan[i1] + bsum[i1 >> 8];
    }
    cnt[t] = 0;
    __syncthreads();
    for (int e = est + t; e < een; e += 256)
        atomicAdd(&cnt[((unsigned)ebuf[e]) >> 24], 1);
    __syncthreads();
    int v = cnt[t];
    pfx[t] = v;
    __syncthreads();
    #pragma unroll
    for (int d = 1; d < 256; d <<= 1) {
        int add = (t >= d) ? pfx[t - d] : 0;
        __syncthreads();
        pfx[t] += add;
        __syncthreads();
    }
    int o = est + pfx[t] - v;
    int seg = b * 256 + t;
    if (seg < nseg) { deg[seg] = v; off[seg] = o; }
    cur[t] = o;
    __syncthreads();
    for (int e = est + t; e < een; e += 256) {
        unsigned u = (unsigned)ebuf[e];
        int p = atomicAdd(&cur[u >> 24], 1);             // LDS atomic
        esrc[p] = (int)(u & 0xffffffu);
    }
}

// ---- mean aggregation, bf16 hi plane, quarter-wave rows ----
__global__ __launch_bounds__(256) void k_gather(
    const unsigned short* __restrict__ h_hi,
    const int* __restrict__ esrc,
    const int* __restrict__ off, const int* __restrict__ deg,
    unsigned short* __restrict__ a_hi, int nseg)
{
    int i = blockIdx.x * 8 + (threadIdx.x >> 5);
    if (i >= nseg) return;
    int l32 = threadIdx.x & 31;
    int q = l32 >> 4;
    int l16 = l32 & 15;
    int cnt = deg[i], st = off[i];
    const uint4* hp = (const uint4*)h_hi;
    float a0 = 0.f, a1 = 0.f, a2 = 0.f, a3 = 0.f;
    float a4 = 0.f, a5 = 0.f, a6 = 0.f, a7 = 0.f;
    int e = q;
    for (; e + 6 < cnt; e += 8) {
        int i0 = esrc[st + e + 0];
        int i1 = esrc[st + e + 2];
        int i2 = esrc[st + e + 4];
        int i3 = esrc[st + e + 6];
        uint4 u0 = hp[(size_t)i0 * 16 + l16];
        uint4 u1 = hp[(size_t)i1 * 16 + l16];
        uint4 u2 = hp[(size_t)i2 * 16 + l16];
        uint4 u3 = hp[(size_t)i3 * 16 + l16];
        a0 += lo16f(u0.x); a1 += hi16f(u0.x); a2 += lo16f(u0.y); a3 += hi16f(u0.y);
        a4 += lo16f(u0.z); a5 += hi16f(u0.z); a6 += lo16f(u0.w); a7 += hi16f(u0.w);
        a0 += lo16f(u1.x); a1 += hi16f(u1.x); a2 += lo16f(u1.y); a3 += hi16f(u1.y);
        a4 += lo16f(u1.z); a5 += hi16f(u1.z); a6 += lo16f(u1.w); a7 += hi16f(u1.w);
        a0 += lo16f(u2.x); a1 += hi16f(u2.x); a2 += lo16f(u2.y); a3 += hi16f(u2.y);
        a4 += lo16f(u2.z); a5 += hi16f(u2.z); a6 += lo16f(u2.w); a7 += hi16f(u2.w);
        a0 += lo16f(u3.x); a1 += hi16f(u3.x); a2 += lo16f(u3.y); a3 += hi16f(u3.y);
        a4 += lo16f(u3.z); a5 += hi16f(u3.z); a6 += lo16f(u3.w); a7 += hi16f(u3.w);
    }
    for (; e < cnt; e += 2) {
        uint4 u = hp[(size_t)esrc[st + e] * 16 + l16];
        a0 += lo16f(u.x); a1 += hi16f(u.x); a2 += lo16f(u.y); a3 += hi16f(u.y);
        a4 += lo16f(u.z); a5 += hi16f(u.z); a6 += lo16f(u.w); a7 += hi16f(u.w);
    }
    a0 += __shfl_xor(a0, 16, 64);
    a1 += __shfl_xor(a1, 16, 64);
    a2 += __shfl_xor(a2, 16, 64);
    a3 += __shfl_xor(a3, 16, 64);
    a4 += __shfl_xor(a4, 16, 64);
    a5 += __shfl_xor(a5, 16, 64);
    a6 += __shfl_xor(a6, 16, 64);
    a7 += __shfl_xor(a7, 16, 64);
    if (q == 0) {
        float inv = 1.0f / (float)(cnt > 1 ? cnt : 1);
        uint4 o;
        o.x = (unsigned int)f2bf(a0 * inv) | ((unsigned int)f2bf(a1 * inv) << 16);
        o.y = (unsigned int)f2bf(a2 * inv) | ((unsigned int)f2bf(a3 * inv) << 16);
        o.z = (unsigned int)f2bf(a4 * inv) | ((unsigned int)f2bf(a5 * inv) << 16);
        o.w = (unsigned int)f2bf(a6 * inv) | ((unsigned int)f2bf(a7 * inv) << 16);
        ((uint4*)a_hi)[(size_t)i * 16 + l16] = o;
    }
}

// ---- pipelined split-bf16 MFMA GEMM (+ optional fused classifier tail) ----
struct GArgs {
    const unsigned short* A_hi[3];
    const unsigned short* A_lo[3];
    const unsigned short* B_hi[3];   // transposed [n][k]
    const unsigned short* B_lo[3];
    int alo[3];
    int blo[3];
    const float* bias;
    const float* prelu;
    unsigned short* C_hi;
    unsigned short* C_lo;
    int M;
    int P;
    // fused classifier (layer-2): active when clsBhi != nullptr
    const unsigned short* clsBhi;    // [n][k] 128x128 bf16 hi plane
    const unsigned short* clsBlo;
    const float* clsBias;
    float* outF;
};

__global__ __launch_bounds__(256) void k_mgemm(GArgs g)
{
    __shared__ unsigned short lds[2][32 * 512];   // 2 x 32 KB
    const int t = threadIdx.x;
    const int w = t >> 6, lane = t & 63;
    const int laneL = lane & 15, laneH = lane >> 4;
    const int wi = w >> 1, wj = w & 1;
    const int m0 = blockIdx.x * 128;
    const int Mm1 = g.M - 1;
    const int S = g.P * 4;

    f32x4 acc[4][4];
    #pragma unroll
    for (int a = 0; a < 4; ++a)
        #pragma unroll
        for (int b = 0; b < 4; ++b)
            acc[a][b] = (f32x4){0.f, 0.f, 0.f, 0.f};

    auto stage = [&](int s, unsigned short* buf) {
        int p = s >> 2, koff = (s & 3) * 32;
        const unsigned short* tp[4];
        tp[0] = g.A_hi[p];
        tp[1] = g.alo[p] ? g.A_lo[p] : nullptr;
        tp[2] = g.B_hi[p];
        tp[3] = g.blo[p] ? g.B_lo[p] : nullptr;
        #pragma unroll
        for (int c = 0; c < 8; ++c) {
            int chunk = w + c * 4;            // 0..31
            int slot = chunk >> 3, j = chunk & 7;
            const unsigned short* plane = tp[slot];
            if (!plane) continue;
            int rc = j * 16 + laneL;
            int row = (slot < 2) ? (m0 + rc <= Mm1 ? m0 + rc : Mm1) : rc;
            const unsigned short* gp = plane + (size_t)row * 128 + koff + laneH * 8;
            gload_lds16(gp, &buf[(slot * 8 + j) * 512]);
        }
    };

    stage(0, lds[0]);
    for (int s = 0; s < S; ++s) {
        unsigned short* cur = lds[s & 1];
        unsigned short* nxt = lds[(s & 1) ^ 1];
        __syncthreads();                      // drains stage(s); frees nxt
        if (s + 1 < S) stage(s + 1, nxt);     // overlaps with compute below
        int p = s >> 2;
        const bool hasAlo = g.alo[p] != 0;
        const bool hasBlo = g.blo[p] != 0;
        const bf16x8* fr = (const bf16x8*)cur;
        bf16x8 ah[4], al[4], bh[4], bl[4];
        #pragma unroll
        for (int mi = 0; mi < 4; ++mi)
            ah[mi] = fr[(0 + wi * 4 + mi) * 64 + lane];
        if (hasAlo) {
            #pragma unroll
            for (int mi = 0; mi < 4; ++mi)
                al[mi] = fr[(8 + wi * 4 + mi) * 64 + lane];
        }
        #pragma unroll
        for (int nj = 0; nj < 4; ++nj)
            bh[nj] = fr[(16 + wj * 4 + nj) * 64 + lane];
        if (hasBlo) {
            #pragma unroll
            for (int nj = 0; nj < 4; ++nj)
                bl[nj] = fr[(24 + wj * 4 + nj) * 64 + lane];
        }
        #pragma unroll
        for (int mi = 0; mi < 4; ++mi)
            #pragma unroll
            for (int nj = 0; nj < 4; ++nj) {
                acc[mi][nj] = __builtin_amdgcn_mfma_f32_16x16x32_bf16(
                    ah[mi], bh[nj], acc[mi][nj], 0, 0, 0);
                if (hasBlo)
                    acc[mi][nj] = __builtin_amdgcn_mfma_f32_16x16x32_bf16(
                        ah[mi], bl[nj], acc[mi][nj], 0, 0, 0);
                if (hasAlo)
                    acc[mi][nj] = __builtin_amdgcn_mfma_f32_16x16x32_bf16(
                        al[mi], bh[nj], acc[mi][nj], 0, 0, 0);
            }
    }

    float bv[4];
    #pragma unroll
    for (int nj = 0; nj < 4; ++nj)
        bv[nj] = g.bias[wj * 64 + nj * 16 + laneL];

    if (g.clsBhi) {
        // ---- fused classifier tail ----
        // (1) swizzled h2 hi/lo planes into lds[0]/lds[1]
        char* l0 = (char*)&lds[0][0];
        char* l1 = (char*)&lds[1][0];
        __syncthreads();
        #pragma unroll
        for (int nj = 0; nj < 4; ++nj) {
            int col = wj * 64 + nj * 16 + laneL;
            #pragma unroll
            for (int mi = 0; mi < 4; ++mi)
                #pragma unroll
                for (int r = 0; r < 4; ++r) {
                    int row = wi * 64 + mi * 16 + laneH * 4 + r;
                    float v = acc[mi][nj][r] + bv[nj];
                    unsigned short h = f2bf(v);
                    int offb = row * 256 + ((col * 2) ^ ((row & 7) << 4));
                    *(unsigned short*)(l0 + offb) = h;
                    *(unsigned short*)(l1 + offb) = f2bf(v - bf2f(h));
                }
        }
        __syncthreads();
        // (2) cls GEMM: A from swizzled LDS, B from global (L2-resident)
        f32x4 acc2[4][4];
        #pragma unroll
        for (int a = 0; a < 4; ++a)
            #pragma unroll
            for (int b = 0; b < 4; ++b)
                acc2[a][b] = (f32x4){0.f, 0.f, 0.f, 0.f};
        #pragma unroll
        for (int ks = 0; ks < 4; ++ks) {
            bf16x8 ah2[4], al2[4], bh2[4], bl2[4];
            #pragma unroll
            for (int mi = 0; mi < 4; ++mi) {
                int rc = wi * 64 + mi * 16 + laneL;
                int aoff = rc * 256 + ((ks * 64 + laneH * 16) ^ ((rc & 7) << 4));
                ah2[mi] = *(const bf16x8*)(l0 + aoff);
                al2[mi] = *(const bf16x8*)(l1 + aoff);
            }
            #pragma unroll
            for (int nj = 0; nj < 4; ++nj) {
                int rc = wj * 64 + nj * 16 + laneL;
                size_t boff = (size_t)rc * 128 + ks * 32 + laneH * 8;
                bh2[nj] = *(const bf16x8*)(g.clsBhi + boff);
                bl2[nj] = *(const bf16x8*)(g.clsBlo + boff);
            }
            #pragma unroll
            for (int mi = 0; mi < 4; ++mi)
                #pragma unroll
                for (int nj = 0; nj < 4; ++nj) {
                    acc2[mi][nj] = __builtin_amdgcn_mfma_f32_16x16x32_bf16(
                        ah2[mi], bh2[nj], acc2[mi][nj], 0, 0, 0);
                    acc2[mi][nj] = __builtin_amdgcn_mfma_f32_16x16x32_bf16(
                        ah2[mi], bl2[nj], acc2[mi][nj], 0, 0, 0);
                    acc2[mi][nj] = __builtin_amdgcn_mfma_f32_16x16x32_bf16(
                        al2[mi], bh2[nj], acc2[mi][nj], 0, 0, 0);
                }
        }
        // (3) fp32 out via 64 KB LDS
        float cb[4];
        #pragma unroll
        for (int nj = 0; nj < 4; ++nj)
            cb[nj] = g.clsBias[wj * 64 + nj * 16 + laneL];
        float* lf = (float*)&lds[0][0];
        __syncthreads();
        #pragma unroll
        for (int nj = 0; nj < 4; ++nj) {
            int col = wj * 64 + nj * 16 + laneL;
            #pragma unroll
            for (int mi = 0; mi < 4; ++mi)
                #pragma unroll
                for (int r = 0; r < 4; ++r) {
                    int row = wi * 64 + mi * 16 + laneH * 4 + r;
                    lf[row * 128 + col] = acc2[mi][nj][r] + cb[nj];
                }
        }
        __syncthreads();
        const uint4* lsrc = (const uint4*)lf;
        #pragma unroll
        for (int it = 0; it < 16; ++it) {
            int idx = it * 256 + t;          // 4096 uint4
            int row = idx >> 5, c = idx & 31;
            int m = m0 + row;
            if (m < g.M)
                ((uint4*)(g.outF + (size_t)m * 128))[c] = lsrc[idx];
        }
        return;
    }

    // ---- single-pass bf16 epilogue: hi -> lds[0], lo -> lds[1] ----
    const bool hasPrelu = (g.prelu != nullptr);
    float av[4];
    #pragma unroll
    for (int nj = 0; nj < 4; ++nj)
        av[nj] = hasPrelu ? g.prelu[wj * 64 + nj * 16 + laneL] : 0.f;

    unsigned short* lph = &lds[0][0];
    unsigned short* lpl = &lds[1][0];
    __syncthreads();
    #pragma unroll
    for (int nj = 0; nj < 4; ++nj) {
        int col = wj * 64 + nj * 16 + laneL;
        #pragma unroll
        for (int mi = 0; mi < 4; ++mi)
            #pragma unroll
            for (int r = 0; r < 4; ++r) {
                int row = wi * 64 + mi * 16 + laneH * 4 + r;
                float v = acc[mi][nj][r] + bv[nj];
                if (hasPrelu) v = v >= 0.f ? v : av[nj] * v;
                unsigned short h = f2bf(v);
                lph[row * 128 + col] = h;
                lpl[row * 128 + col] = f2bf(v - bf2f(h));
            }
    }
    __syncthreads();
    {
        const uint4* sh = (const uint4*)lph;
        const uint4* sl = (const uint4*)lpl;
        #pragma unroll
        for (int it = 0; it < 8; ++it) {
            int idx = it * 256 + t;          // 2048 uint4 per plane
            int row = idx >> 4, c = idx & 15;
            int m = m0 + row;
            if (m < g.M) {
                ((uint4*)(g.C_hi + (size_t)m * 128))[c] = sh[idx];
                ((uint4*)(g.C_lo + (size_t)m * 128))[c] = sl[idx];
            }
        }
    }
}

extern "C" void kernel_launch(void* const* d_in, const int* in_sizes, int n_in,
                              void* d_out, int out_size, void* d_ws, size_t ws_size,
                              hipStream_t stream) {
    const float* x      = (const float*)d_in[0];
    const int*   ei     = (const int*)d_in[1];
    const int*   et     = (const int*)d_in[2];
    const float* Wnum   = (const float*)d_in[3];
    const float* bnum   = (const float*)d_in[4];
    const float* Wcat   = (const float*)d_in[5];
    const float* bcat   = (const float*)d_in[6];
    const float* Win    = (const float*)d_in[7];
    const float* bin    = (const float*)d_in[8];
    const float* pa     = (const float*)d_in[9];
    const float* Wrel1  = (const float*)d_in[10];
    const float* Wroot1 = (const float*)d_in[11];
    const float* brg1   = (const float*)d_in[12];
    const float* Wrel2  = (const float*)d_in[13];
    const float* Wroot2 = (const float*)d_in[14];
    const float* brg2   = (const float*)d_in[15];
    const float* Wcls   = (const float*)d_in[16];
    const float* bcls   = (const float*)d_in[17];
    float* out = (float*)d_out;

    const int N = in_sizes[0] / 8;
    const int E = in_sizes[1] / 2;
    const int nseg = 2 * N;
    const size_t NH = (size_t)N * 128;

    const int NBLK  = (E + 4095) / 4096;        // edge blocks (391)
    const int NBINS = (nseg + 255) / 256;       // coarse bins (782)
    const long long L = (long long)NBINS * NBLK;

    char* w = (char*)d_ws;
    unsigned short* h1_hi = (unsigned short*)w;  w += NH * 2;   // layer-1 out (ws)
    unsigned short* h1_lo = (unsigned short*)w;  w += NH * 2;
    unsigned short* agg_hi = (unsigned short*)w; w += 2 * NH * 2;
    int* deg      = (int*)w;  w += (size_t)nseg * 4;
    int* off      = (int*)w;  w += (size_t)nseg * 4;
    int* cntmatT  = (int*)w;  w += (size_t)L * 4;   // [blk][bin]
    int* cntmat   = (int*)w;  w += (size_t)L * 4;   // [bin][blk]
    int* cntscan  = (int*)w;  w += (size_t)L * 4;   // [bin][blk] local-scanned
    int* cntscanT = (int*)w;  w += (size_t)L * 4;   // [blk][bin] global-scanned
    int* esrc     = (int*)w;  w += (size_t)E * 4;
    int* bsum     = (int*)w;  w += 4096 * 4;
    unsigned short* wplanes = (unsigned short*)w;  w += 8 * 2 * 16384 * 2;

    // d_out triple duty (serialized by stream order):
    //  CSR: ebuf (E ints) -> egemm: h0 planes -> layer-2 fused: fp32 out
    int* ebuf = (int*)d_out;
    unsigned short* h0_hi = (unsigned short*)d_out;
    unsigned short* h0_lo = h0_hi + NH;

    unsigned short* whi[8];
    unsigned short* wlo[8];
    for (int i = 0; i < 8; ++i) {
        whi[i] = wplanes + (size_t)i * 2 * 16384;
        wlo[i] = whi[i] + 16384;
    }

    const int gm = (N + 127) / 128;
    const int gg = (nseg + 7) / 8;

    // merged weight split + bin histogram
    {
        WHArgs a;
        a.W[0] = Win;   a.W[1] = Wroot1; a.W[2] = Wrel1; a.W[3] = Wrel1 + 16384;
        a.W[4] = Wroot2; a.W[5] = Wrel2; a.W[6] = Wrel2 + 16384; a.W[7] = Wcls;
        for (int i = 0; i < 8; ++i) { a.hi[i] = whi[i]; a.lo[i] = wlo[i]; }
        a.ei = ei; a.et = et; a.cntmatT = cntmatT;
        a.E = E; a.N = N; a.NBINS = NBINS;
        k_wsplit_hist<<<512 + NBLK, 256, 0, stream>>>(a);
    }

    k_transpose<<<((NBLK + 31) / 32) * ((NBINS + 31) / 32), 256, 0, stream>>>(
        cntmatT, cntmat, NBLK, NBINS);

    const int nb1 = (int)((L + 255) / 256);
    k_scan1<<<nb1, 256, 0, stream>>>(cntmat, cntscan, bsum, (int)L);
    k_scan2<<<1, 1024, 0, stream>>>(bsum, nb1);
    k_transpose_add<<<((NBINS + 31) / 32) * ((NBLK + 31) / 32), 256, 0, stream>>>(
        cntscan, cntscanT, bsum, NBINS, NBLK);

    k_binscatter<<<NBLK, 256, 0, stream>>>(ei, et, cntscanT, ebuf, E, N, NBINS);
    k_bincsr<<<NBINS, 256, 0, stream>>>(cntscan, bsum, ebuf, deg, off, esrc,
                                        E, nseg, NBLK, NBINS);

    // fused embed GEMM (x -> h0 planes in d_out; ebuf dead after bincsr)
    k_egemm<<<gm, 256, 0, stream>>>(x, Wnum, bnum, Wcat, bcat,
                                    whi[0], wlo[0], bin, pa,
                                    h0_hi, h0_lo, N);

    // layer 1: gather(h0) -> agg; GEMM -> h1 (ws)
    k_gather<<<gg, 256, 0, stream>>>(h0_hi, esrc, off, deg, agg_hi, nseg);
    {
        GArgs g = {};
        g.A_hi[0] = h0_hi;       g.A_lo[0] = h0_lo;  g.alo[0] = 1; g.blo[0] = 1;
        g.A_hi[1] = agg_hi;      g.alo[1] = 0;       g.blo[1] = 0;
        g.A_hi[2] = agg_hi + NH; g.alo[2] = 0;       g.blo[2] = 0;
        g.B_hi[0] = whi[1]; g.B_lo[0] = wlo[1];
        g.B_hi[1] = whi[2]; g.B_lo[1] = wlo[2];
        g.B_hi[2] = whi[3]; g.B_lo[2] = wlo[3];
        g.bias = brg1; g.prelu = nullptr;
        g.C_hi = h1_hi; g.C_lo = h1_lo;
        g.M = N; g.P = 3;
        g.clsBhi = nullptr;
        k_mgemm<<<gm, 256, 0, stream>>>(g);
    }
    // layer 2 + fused classifier: gather(h1) -> agg; GEMM+cls -> out (d_out)
    k_gather<<<gg, 256, 0, stream>>>(h1_hi, esrc, off, deg, agg_hi, nseg);
    {
        GArgs g = {};
        g.A_hi[0] = h1_hi;       g.A_lo[0] = h1_lo;  g.alo[0] = 1; g.blo[0] = 1;
        g.A_hi[1] = agg_hi;      g.alo[1] = 0;       g.blo[1] = 0;
        g.A_hi[2] = agg_hi + NH; g.alo[2] = 0;       g.blo[2] = 0;
        g.B_hi[0] = whi[4]; g.B_lo[0] = wlo[4];
        g.B_hi[1] = whi[5]; g.B_lo[1] = wlo[5];
        g.B_hi[2] = whi[6]; g.B_lo[2] = wlo[6];
        g.bias = brg2; g.prelu = nullptr;
        g.C_hi = nullptr; g.C_lo = nullptr;
        g.M = N; g.P = 3;
        g.clsBhi = whi[7]; g.clsBlo = wlo[7];
        g.clsBias = bcls; g.outF = out;
        k_mgemm<<<gm, 256, 0, stream>>>(g);
    }
}